// Round 1
// baseline (877.006 us; speedup 1.0000x reference)
//
#include <hip/hip_runtime.h>
#include <cstddef>

#define B_  8
#define C_  256
#define H_  64
#define W_  64
#define P_  4096
#define M_  8
#define K_  4
#define Cm_ 32

// ---------------------------------------------------------------------------
// Kernel 1: fused 3x3 conv producing offsets (64 ch) + attn logits (32 ch)
// block: 512 threads; grid (B, H/2). Each block: batch b, output rows y0,y0+1.
// Per ic: stage 4 input rows (zero-padded) + 96x9 weights in LDS, accumulate.
// ---------------------------------------------------------------------------
__global__ __launch_bounds__(512) void conv3x3_96(
    const float* __restrict__ in,      // (B,256,64,64)
    const float* __restrict__ off_w,   // (64,256,3,3)
    const float* __restrict__ off_b,   // (64)
    const float* __restrict__ attn_w,  // (32,256,3,3)
    const float* __restrict__ attn_b,  // (32)
    float* __restrict__ offs,          // (B,64,64,64)
    float* __restrict__ attn)          // (B,32,64,64)
{
    const int b     = blockIdx.x;
    const int y0    = blockIdx.y * 2;
    const int tid   = threadIdx.x;
    const int x     = tid & 63;
    const int wv    = tid >> 6;        // wave id 0..7

    __shared__ float rows[4][68];      // input rows y0-1..y0+2, col 0 = x=-1 pad
    __shared__ float wsm[96][12];      // 9 weights per oc, padded to 12

    float acc[12][2];
    #pragma unroll
    for (int j = 0; j < 12; ++j) { acc[j][0] = 0.f; acc[j][1] = 0.f; }

    const float* inb = in + (size_t)b * C_ * P_;

    for (int ic = 0; ic < C_; ++ic) {
        // stage input rows (256 elems) + boundary pads
        if (tid < 256) {
            int r = tid >> 6, xx = tid & 63;
            int gy = y0 - 1 + r;
            float v = (gy >= 0 && gy < H_) ? inb[(size_t)ic * P_ + gy * W_ + xx] : 0.f;
            rows[r][1 + xx] = v;
        } else if (tid < 264) {
            int t = tid - 256;
            rows[t >> 1][(t & 1) ? 65 : 0] = 0.f;
        }
        // stage weights: 96 oc x 9
        for (int idx = tid; idx < 864; idx += 512) {
            int oc = idx / 9, r = idx - oc * 9;
            float wval;
            if (oc < 64) wval = off_w[((size_t)oc * C_ + ic) * 9 + r];
            else         wval = attn_w[((size_t)(oc - 64) * C_ + ic) * 9 + r];
            wsm[oc][r] = wval;
        }
        __syncthreads();

        float rv[4][3];
        #pragma unroll
        for (int r = 0; r < 4; ++r)
            #pragma unroll
            for (int c = 0; c < 3; ++c)
                rv[r][c] = rows[r][x + c];

        #pragma unroll
        for (int j = 0; j < 12; ++j) {
            const int oc = j * 8 + wv;
            const float* wp = &wsm[oc][0];
            const float w0 = wp[0], w1 = wp[1], w2 = wp[2],
                        w3 = wp[3], w4 = wp[4], w5 = wp[5],
                        w6 = wp[6], w7 = wp[7], w8 = wp[8];
            #pragma unroll
            for (int ry = 0; ry < 2; ++ry) {
                acc[j][ry] += w0 * rv[ry][0]     + w1 * rv[ry][1]     + w2 * rv[ry][2]
                            + w3 * rv[ry + 1][0] + w4 * rv[ry + 1][1] + w5 * rv[ry + 1][2]
                            + w6 * rv[ry + 2][0] + w7 * rv[ry + 2][1] + w8 * rv[ry + 2][2];
            }
        }
        __syncthreads();
    }

    #pragma unroll
    for (int j = 0; j < 12; ++j) {
        const int oc = j * 8 + wv;
        #pragma unroll
        for (int ry = 0; ry < 2; ++ry) {
            const int y = y0 + ry;
            if (oc < 64)
                offs[((size_t)(b * 64 + oc)) * P_ + y * W_ + x] = acc[j][ry] + off_b[oc];
            else
                attn[((size_t)(b * 32 + (oc - 64))) * P_ + y * W_ + x] = acc[j][ry] + attn_b[oc - 64];
        }
    }
}

// ---------------------------------------------------------------------------
// Kernel 2: 1x1 conv = GEMM  out[b,oc,p] = sum_ic w[oc,ic]*x[b,ic,p] + bias
// optional residual add and relu. 64x64 tile, K-tile 16, 256 threads,
// 4x4 micro-tile per thread via float4 LDS reads.
// ---------------------------------------------------------------------------
__global__ __launch_bounds__(256) void gemm1x1(
    const float* __restrict__ x,     // (B, IC, 4096)
    const float* __restrict__ w,     // (OC, IC)
    const float* __restrict__ bias,  // (OC)
    const float* __restrict__ res,   // (B, OC, 4096) or nullptr
    float* __restrict__ out,         // (B, OC, 4096)
    int IC, int OC, int relu)
{
    const int b   = blockIdx.z;
    const int p0  = blockIdx.x * 64;
    const int oc0 = blockIdx.y * 64;
    const int tid = threadIdx.x;
    const int tx  = tid & 15;   // p quad
    const int ty  = tid >> 4;   // oc quad

    __shared__ float ws_[16][68];
    __shared__ float xs_[16][68];

    const float* xb = x + (size_t)b * IC * P_;

    float acc[4][4] = {};

    for (int k0 = 0; k0 < IC; k0 += 16) {
        {
            const int oc_l = tid >> 2, kq = (tid & 3) * 4;
            const float4 wv = *(const float4*)&w[(size_t)(oc0 + oc_l) * IC + k0 + kq];
            ws_[kq + 0][oc_l] = wv.x; ws_[kq + 1][oc_l] = wv.y;
            ws_[kq + 2][oc_l] = wv.z; ws_[kq + 3][oc_l] = wv.w;
        }
        {
            const int kk = tid >> 4, pq = (tid & 15) * 4;
            const float4 xv = *(const float4*)&xb[(size_t)(k0 + kk) * P_ + p0 + pq];
            *(float4*)&xs_[kk][pq] = xv;
        }
        __syncthreads();
        #pragma unroll
        for (int kk = 0; kk < 16; ++kk) {
            const float4 a  = *(const float4*)&ws_[kk][ty * 4];
            const float4 bb = *(const float4*)&xs_[kk][tx * 4];
            acc[0][0] += a.x * bb.x; acc[0][1] += a.x * bb.y; acc[0][2] += a.x * bb.z; acc[0][3] += a.x * bb.w;
            acc[1][0] += a.y * bb.x; acc[1][1] += a.y * bb.y; acc[1][2] += a.y * bb.z; acc[1][3] += a.y * bb.w;
            acc[2][0] += a.z * bb.x; acc[2][1] += a.z * bb.y; acc[2][2] += a.z * bb.z; acc[2][3] += a.z * bb.w;
            acc[3][0] += a.w * bb.x; acc[3][1] += a.w * bb.y; acc[3][2] += a.w * bb.z; acc[3][3] += a.w * bb.w;
        }
        __syncthreads();
    }

    #pragma unroll
    for (int i = 0; i < 4; ++i) {
        const int oc = oc0 + ty * 4 + i;
        const float bi = bias[oc];
        float4 o = make_float4(acc[i][0] + bi, acc[i][1] + bi, acc[i][2] + bi, acc[i][3] + bi);
        const size_t idx = (size_t)b * OC * P_ + (size_t)oc * P_ + p0 + tx * 4;
        if (res) {
            const float4 r4 = *(const float4*)&res[idx];
            o.x += r4.x; o.y += r4.y; o.z += r4.z; o.w += r4.w;
        }
        if (relu) {
            o.x = fmaxf(o.x, 0.f); o.y = fmaxf(o.y, 0.f);
            o.z = fmaxf(o.z, 0.f); o.w = fmaxf(o.w, 0.f);
        }
        *(float4*)&out[idx] = o;
    }
}

// ---------------------------------------------------------------------------
// Kernel 3: softmax over K + bilinear grid-sample (zero pad) + weighted sum
// block: 256 threads = (x 0..63) x (4 channel groups of 8). grid (y, m, b).
// ---------------------------------------------------------------------------
__global__ __launch_bounds__(256) void sample_attend(
    const float* __restrict__ value,  // (B,256,4096)
    const float* __restrict__ offs,   // (B,64,4096)
    const float* __restrict__ attn,   // (B,32,4096)
    float* __restrict__ out1)         // (B,256,4096)
{
    const int y   = blockIdx.x;
    const int m   = blockIdx.y;
    const int b   = blockIdx.z;
    const int tid = threadIdx.x;
    const int x   = tid & 63;
    const int g   = tid >> 6;          // channel group: cm = g*8 .. g*8+7

    float a[4];
    #pragma unroll
    for (int k = 0; k < 4; ++k)
        a[k] = attn[((size_t)b * 32 + m * 4 + k) * P_ + y * W_ + x];
    const float mx = fmaxf(fmaxf(a[0], a[1]), fmaxf(a[2], a[3]));
    float s = 0.f;
    #pragma unroll
    for (int k = 0; k < 4; ++k) { a[k] = __expf(a[k] - mx); s += a[k]; }
    const float inv = 1.f / s;

    float acc[8] = {};
    const float* vb = value + ((size_t)b * 256 + m * 32 + g * 8) * P_;

    #pragma unroll
    for (int k = 0; k < 4; ++k) {
        const float offx = offs[((size_t)b * 64 + (m * 4 + k) * 2 + 0) * P_ + y * W_ + x];
        const float offy = offs[((size_t)b * 64 + (m * 4 + k) * 2 + 1) * P_ + y * W_ + x];
        const float px = (float)(W_ - 1 - x) + offx;
        const float py = (float)y + offy;
        const float x0f = floorf(px), y0f = floorf(py);
        const int x0 = (int)x0f, yy0 = (int)y0f;
        const float wx = px - x0f, wy = py - y0f;
        const int x1 = x0 + 1, y1 = yy0 + 1;
        const bool vx0 = (x0 >= 0) & (x0 <= 63), vx1 = (x1 >= 0) & (x1 <= 63);
        const bool vy0 = (yy0 >= 0) & (yy0 <= 63), vy1 = (y1 >= 0) & (y1 <= 63);
        const int cx0 = min(max(x0, 0), 63), cx1 = min(max(x1, 0), 63);
        const int cy0 = min(max(yy0, 0), 63), cy1 = min(max(y1, 0), 63);
        const float ak = a[k] * inv;
        const float c00 = ak * (1.f - wx) * (1.f - wy) * ((vx0 & vy0) ? 1.f : 0.f);
        const float c01 = ak * wx * (1.f - wy) * ((vx1 & vy0) ? 1.f : 0.f);
        const float c10 = ak * (1.f - wx) * wy * ((vx0 & vy1) ? 1.f : 0.f);
        const float c11 = ak * wx * wy * ((vx1 & vy1) ? 1.f : 0.f);
        const int i00 = cy0 * 64 + cx0, i01 = cy0 * 64 + cx1;
        const int i10 = cy1 * 64 + cx0, i11 = cy1 * 64 + cx1;
        #pragma unroll
        for (int cm = 0; cm < 8; ++cm) {
            const float* vc = vb + (size_t)cm * P_;
            acc[cm] += c00 * vc[i00] + c01 * vc[i01] + c10 * vc[i10] + c11 * vc[i11];
        }
    }
    #pragma unroll
    for (int cm = 0; cm < 8; ++cm)
        out1[((size_t)b * 256 + m * 32 + g * 8 + cm) * P_ + y * W_ + x] = acc[cm];
}

// ---------------------------------------------------------------------------
extern "C" void kernel_launch(void* const* d_in, const int* in_sizes, int n_in,
                              void* d_out, int out_size, void* d_ws, size_t ws_size,
                              hipStream_t stream) {
    const float* f_recalib = (const float*)d_in[0];
    const float* f_orig    = (const float*)d_in[1];
    const float* offset_w  = (const float*)d_in[2];
    const float* offset_b  = (const float*)d_in[3];
    const float* attn_w    = (const float*)d_in[4];
    const float* attn_b    = (const float*)d_in[5];
    const float* value_w   = (const float*)d_in[6];
    const float* value_b   = (const float*)d_in[7];
    const float* proj_w    = (const float*)d_in[8];
    const float* proj_b    = (const float*)d_in[9];
    const float* mlp_w1    = (const float*)d_in[10];
    const float* mlp_b1    = (const float*)d_in[11];
    const float* mlp_w2    = (const float*)d_in[12];
    const float* mlp_b2    = (const float*)d_in[13];
    float* out = (float*)d_out;

    float* ws    = (float*)d_ws;
    float* offs  = ws;                   // 2,097,152 floats (8 MB)
    float* attn  = offs + 2097152;       // 1,048,576 (4 MB)
    float* value = attn + 1048576;       // 8,388,608 (32 MB)
    float* out1  = value + 8388608;      // 8,388,608 (32 MB)  -> 80 MB total
    float* h     = ws;                   // 16,777,216 (64 MB), aliases dead offs/attn/value/out1-head

    // 1. offsets + attn logits (3x3 convs)
    conv3x3_96<<<dim3(8, 32), 512, 0, stream>>>(
        f_recalib, offset_w, offset_b, attn_w, attn_b, offs, attn);

    // 2. value = 1x1 conv
    gemm1x1<<<dim3(64, 4, 8), 256, 0, stream>>>(
        f_recalib, value_w, value_b, nullptr, value, 256, 256, 0);

    // 3. softmax + grid sample + weighted sum -> out1
    sample_attend<<<dim3(64, 8, 8), 256, 0, stream>>>(value, offs, attn, out1);

    // 4. out2 = proj(out1) + f_orig   -> d_out
    gemm1x1<<<dim3(64, 4, 8), 256, 0, stream>>>(
        out1, proj_w, proj_b, f_orig, out, 256, 256, 0);

    // 5. h = relu(mlp1(out2))
    gemm1x1<<<dim3(64, 8, 8), 256, 0, stream>>>(
        out, mlp_w1, mlp_b1, nullptr, h, 256, 512, 1);

    // 6. out = mlp2(h) + out2  (in-place residual on d_out)
    gemm1x1<<<dim3(64, 4, 8), 256, 0, stream>>>(
        h, mlp_w2, mlp_b2, out, out, 512, 256, 0);
}

// Round 2
// 265.181 us; speedup vs baseline: 3.3072x; 3.3072x over previous
//
#include <hip/hip_runtime.h>
#include <cstddef>

#define P_ 4096

using u16 = unsigned short;
typedef float f32x4 __attribute__((ext_vector_type(4)));
typedef u16   u16x8 __attribute__((ext_vector_type(8)));
typedef u16   u16x4 __attribute__((ext_vector_type(4)));

#define DEVINL __device__ __forceinline__

DEVINL u16 f2bf(float f) {
    union { float f; unsigned u; } v; v.f = f;
    unsigned r = v.u + 0x7fffu + ((v.u >> 16) & 1u);
    return (u16)(r >> 16);
}
DEVINL float bf2f(u16 h) {
    union { unsigned u; float f; } v; v.u = ((unsigned)h) << 16;
    return v.f;
}

DEVINL f32x4 mfma16(u16x8 a, u16x8 b, f32x4 c) {
    asm volatile("v_mfma_f32_16x16x32_bf16 %0, %1, %2, %0"
                 : "+v"(c) : "v"(a), "v"(b));
    return c;
}

DEVINL void gload16(const u16* src, const u16* lds_dst) {
    __builtin_amdgcn_global_load_lds(
        (const __attribute__((address_space(1))) void*)src,
        (__attribute__((address_space(3))) void*)lds_dst, 16, 0, 0);
}

// ---------------------------------------------------------------------------
// prep_weights: all weights -> bf16. conv weights reordered to [tap][96][256].
// ---------------------------------------------------------------------------
__global__ void prep_weights(const float* __restrict__ off_w, const float* __restrict__ attn_w,
                             const float* __restrict__ val_w, const float* __restrict__ proj_w,
                             const float* __restrict__ w1, const float* __restrict__ w2,
                             u16* __restrict__ wbf) {
    int idx = blockIdx.x * 256 + threadIdx.x;
    if (idx >= 614400) return;
    float v;
    if (idx < 221184) {
        int tap = idx / 24576, rem = idx - tap * 24576, oc = rem >> 8, ic = rem & 255;
        v = (oc < 64) ? off_w[(size_t)(oc * 256 + ic) * 9 + tap]
                      : attn_w[(size_t)((oc - 64) * 256 + ic) * 9 + tap];
    } else if (idx < 286720) v = val_w[idx - 221184];
    else if (idx < 352256)   v = proj_w[idx - 286720];
    else if (idx < 483328)   v = w1[idx - 352256];
    else                     v = w2[idx - 483328];
    wbf[idx] = f2bf(v);
}

// ---------------------------------------------------------------------------
// NCHW fp32 -> NHWC bf16 (LDS-tiled transpose). grid (64, C/64, B), 256 thr.
// ---------------------------------------------------------------------------
__global__ __launch_bounds__(256) void to_nhwc_bf16(const float* __restrict__ in,
                                                    u16* __restrict__ out, int C) {
    const int px0 = blockIdx.x * 64, c0 = blockIdx.y * 64, b = blockIdx.z;
    __shared__ u16 ts[64 * 72];
    const int t = threadIdx.x, cl = t >> 4, xq = t & 15;
    #pragma unroll
    for (int r = 0; r < 4; ++r) {
        const int c = r * 16 + cl;
        const float4 v = *(const float4*)&in[((size_t)(b * C + c0 + c)) * P_ + px0 + xq * 4];
        ts[(xq * 4 + 0) * 72 + c] = f2bf(v.x);
        ts[(xq * 4 + 1) * 72 + c] = f2bf(v.y);
        ts[(xq * 4 + 2) * 72 + c] = f2bf(v.z);
        ts[(xq * 4 + 3) * 72 + c] = f2bf(v.w);
    }
    __syncthreads();
    const int px = t >> 2, seg = t & 3;
    u16x8 o0, o1;
    #pragma unroll
    for (int j = 0; j < 8; ++j) {
        o0[j] = ts[px * 72 + seg * 16 + j];
        o1[j] = ts[px * 72 + seg * 16 + 8 + j];
    }
    const size_t base = ((size_t)(b * P_ + px0 + px)) * C + c0 + seg * 16;
    *(u16x8*)&out[base]     = o0;
    *(u16x8*)&out[base + 8] = o1;
}

// ---------------------------------------------------------------------------
// conv3x3 as 9 shifted-tap MFMA GEMMs. grid (64 y, 8 b), 256 thr (4 waves).
// Block: one (b,y) row = 64 px, 96 oc, K=2304. LDS: 3 input rows (swizzled,
// via global_load_lds) + all 9 taps' weights for the 64-ic chunk.
// Output NHWC bf16 [b][px][96]: ch 0..63 = offsets, 64..95 = attn logits.
// ---------------------------------------------------------------------------
__global__ __launch_bounds__(256) void conv3x3_mfma(
    const u16* __restrict__ xbf, const u16* __restrict__ wconv,
    const float* __restrict__ off_b, const float* __restrict__ attn_b,
    u16* __restrict__ convout) {
    const int y = blockIdx.x, b = blockIdx.y;
    const int tid = threadIdx.x, w = tid >> 6, lane = tid & 63, g = lane >> 4, i = lane & 15;
    const int wm = w & 1, wn = w >> 1;
    __shared__ u16 xs[3 * 64 * 64];      // [row r][x 64][ic 64] swizzled chunks
    __shared__ u16 wsL[9 * 96 * 72];     // [tap][oc 96][72 pad]

    f32x4 acc[2][3];
    #pragma unroll
    for (int mi = 0; mi < 2; ++mi)
        #pragma unroll
        for (int nj = 0; nj < 3; ++nj) acc[mi][nj] = (f32x4){0.f, 0.f, 0.f, 0.f};

    for (int cc = 0; cc < 4; ++cc) {
        const int ic0 = cc * 64;
        #pragma unroll
        for (int r = 0; r < 3; ++r) {
            const int yy = y + r - 1;
            if (yy >= 0 && yy < 64) {
                for (int ii = w; ii < 8; ii += 4) {
                    const int x = ii * 8 + (lane >> 3), c = lane & 7;
                    const u16* src = xbf + ((size_t)(b * P_ + yy * 64 + x)) * 256 + ic0
                                     + ((c ^ (x & 7)) << 3);
                    gload16(src, &xs[r * 4096 + ii * 512]);
                }
            }
        }
        for (int q = tid; q < 6912; q += 256) {
            const int tap = q / 768, rem = q - tap * 768, oc = rem >> 3, c = rem & 7;
            const u16x8 v = *(const u16x8*)&wconv[((size_t)(tap * 96 + oc)) * 256 + ic0 + (c << 3)];
            *(u16x8*)&wsL[tap * 6912 + oc * 72 + (c << 3)] = v;
        }
        __syncthreads();
        for (int tap = 0; tap < 9; ++tap) {
            const int dy = tap / 3, dx = tap - dy * 3;
            const int yy = y + dy - 1;
            if ((unsigned)yy >= 64u) continue;
            #pragma unroll
            for (int ks = 0; ks < 2; ++ks) {
                u16x8 a[2];
                #pragma unroll
                for (int mi = 0; mi < 2; ++mi) {
                    const int x = (wm * 2 + mi) * 16 + i;
                    const int xsh = x + dx - 1;
                    if ((unsigned)xsh < 64u)
                        a[mi] = *(const u16x8*)&xs[dy * 4096 + xsh * 64
                                                   + (((ks * 4 + g) ^ (xsh & 7)) << 3)];
                    else
                        a[mi] = (u16x8){0, 0, 0, 0, 0, 0, 0, 0};
                }
                #pragma unroll
                for (int nj = 0; nj < 3; ++nj) {
                    const int nt = wn * 3 + nj;
                    const u16x8 bb = *(const u16x8*)&wsL[tap * 6912 + (nt * 16 + i) * 72
                                                         + ((ks * 4 + g) << 3)];
                    acc[0][nj] = mfma16(a[0], bb, acc[0][nj]);
                    acc[1][nj] = mfma16(a[1], bb, acc[1][nj]);
                }
            }
        }
        __syncthreads();
    }
    asm volatile("s_nop 7\n\ts_nop 7" :::);
    #pragma unroll
    for (int mi = 0; mi < 2; ++mi) {
        const int x0 = (wm * 2 + mi) * 16 + g * 4;
        #pragma unroll
        for (int nj = 0; nj < 3; ++nj) {
            const int oc = (wn * 3 + nj) * 16 + i;
            const float bv = (oc < 64) ? off_b[oc] : attn_b[oc - 64];
            #pragma unroll
            for (int r = 0; r < 4; ++r)
                convout[((size_t)(b * P_ + y * 64 + x0 + r)) * 96 + oc] =
                    f2bf(acc[mi][nj][r] + bv);
        }
    }
}

// ---------------------------------------------------------------------------
// NHWC bf16 MFMA GEMM: out[px][oc] = sum_k X[px][k] * W[oc][k]  (per batch)
// mode 0: +bias -> bf16 NHWC; mode 1: +bias,relu -> bf16 NHWC;
// mode 2: +bias +resid(NCHW f32) -> f32 NCHW (LDS transpose epilogue).
// grid (64, OC/64, 8), 256 thr. Tile 64px x 64oc, K chunked by 256.
// ---------------------------------------------------------------------------
__global__ __launch_bounds__(256) void gemm_nhwc(
    const u16* __restrict__ X, const u16* __restrict__ W,
    const float* __restrict__ bias, const float* __restrict__ resid,
    void* __restrict__ outp, const int KTOT, const int OC, const int mode) {
    const int px0 = blockIdx.x * 64, oc0 = blockIdx.y * 64, b = blockIdx.z;
    const int tid = threadIdx.x, w = tid >> 6, lane = tid & 63, g = lane >> 4, i = lane & 15;
    const int wm = (w & 1) * 2, wn = (w >> 1) * 2;
    __shared__ u16 xs[64 * 256];     // [px][256k] swizzled 16B chunks
    __shared__ u16 wsL[64 * 264];    // [oc][264 pad]

    f32x4 acc[2][2];
    #pragma unroll
    for (int mi = 0; mi < 2; ++mi)
        #pragma unroll
        for (int nj = 0; nj < 2; ++nj) acc[mi][nj] = (f32x4){0.f, 0.f, 0.f, 0.f};

    for (int kc = 0; kc < KTOT; kc += 256) {
        for (int ii = w; ii < 32; ii += 4) {
            const int px = ii * 2 + (lane >> 5), c = lane & 31;
            const u16* src = X + ((size_t)(b * P_ + px0 + px)) * KTOT + kc
                             + ((c ^ (px & 7)) << 3);
            gload16(src, &xs[ii * 512]);
        }
        for (int q = tid; q < 2048; q += 256) {
            const int oc = q >> 5, c = q & 31;
            const u16x8 v = *(const u16x8*)&W[(size_t)(oc0 + oc) * KTOT + kc + (c << 3)];
            *(u16x8*)&wsL[oc * 264 + (c << 3)] = v;
        }
        __syncthreads();
        #pragma unroll
        for (int ks = 0; ks < 8; ++ks) {
            u16x8 a[2], bb[2];
            #pragma unroll
            for (int mi = 0; mi < 2; ++mi) {
                const int px = (wm + mi) * 16 + i;
                a[mi] = *(const u16x8*)&xs[px * 256 + (((ks * 4 + g) ^ (px & 7)) << 3)];
            }
            #pragma unroll
            for (int nj = 0; nj < 2; ++nj)
                bb[nj] = *(const u16x8*)&wsL[((wn + nj) * 16 + i) * 264 + ((ks * 4 + g) << 3)];
            acc[0][0] = mfma16(a[0], bb[0], acc[0][0]);
            acc[1][0] = mfma16(a[1], bb[0], acc[1][0]);
            acc[0][1] = mfma16(a[0], bb[1], acc[0][1]);
            acc[1][1] = mfma16(a[1], bb[1], acc[1][1]);
        }
        __syncthreads();
    }
    asm volatile("s_nop 7\n\ts_nop 7" :::);

    if (mode < 2) {
        u16* out = (u16*)outp;
        #pragma unroll
        for (int mi = 0; mi < 2; ++mi) {
            #pragma unroll
            for (int nj = 0; nj < 2; ++nj) {
                const int ocg = oc0 + (wn + nj) * 16 + i;
                const float bv = bias[ocg];
                #pragma unroll
                for (int r = 0; r < 4; ++r) {
                    const int px = px0 + (wm + mi) * 16 + g * 4 + r;
                    float v = acc[mi][nj][r] + bv;
                    if (mode == 1) v = fmaxf(v, 0.f);
                    out[((size_t)(b * P_ + px)) * OC + ocg] = f2bf(v);
                }
            }
        }
    } else {
        float* lf = (float*)xs;   // 64 x 68 f32 = 17408 B, fits in xs
        #pragma unroll
        for (int mi = 0; mi < 2; ++mi) {
            #pragma unroll
            for (int nj = 0; nj < 2; ++nj) {
                const int ocl = (wn + nj) * 16 + i;
                const float bv = bias[oc0 + ocl];
                #pragma unroll
                for (int r = 0; r < 4; ++r) {
                    const int pxl = (wm + mi) * 16 + g * 4 + r;
                    lf[ocl * 68 + pxl] = acc[mi][nj][r] + bv;
                }
            }
        }
        __syncthreads();
        float* out = (float*)outp;
        const int ocl = tid >> 2, pq = (tid & 3) * 16;
        const size_t base = ((size_t)b * OC + oc0 + ocl) * P_ + px0 + pq;
        #pragma unroll
        for (int j = 0; j < 16; ++j)
            out[base + j] = lf[ocl * 68 + pq + j] + resid[base + j];
    }
}

// ---------------------------------------------------------------------------
// softmax over K + bilinear grid-sample + weighted sum. NHWC bf16 in/out.
// grid (64 y, 8 m, 8 b), 256 thr: x = tid>>2, channel-group gq = tid&3.
// ---------------------------------------------------------------------------
__global__ __launch_bounds__(256) void sample_attend_bf(
    const u16* __restrict__ value, const u16* __restrict__ conv,
    u16* __restrict__ out1) {
    const int y = blockIdx.x, m = blockIdx.y, b = blockIdx.z;
    const int tid = threadIdx.x, x = tid >> 2, gq = tid & 3;
    const size_t prow = (size_t)(b * P_ + y * 64 + x);

    const u16x8 ov = *(const u16x8*)&conv[prow * 96 + m * 8];
    const u16x4 av = *(const u16x4*)&conv[prow * 96 + 64 + m * 4];

    float a[4];
    #pragma unroll
    for (int k = 0; k < 4; ++k) a[k] = bf2f(av[k]);
    const float mx = fmaxf(fmaxf(a[0], a[1]), fmaxf(a[2], a[3]));
    float s = 0.f;
    #pragma unroll
    for (int k = 0; k < 4; ++k) { a[k] = __expf(a[k] - mx); s += a[k]; }
    const float inv = 1.f / s;

    float acc[8];
    #pragma unroll
    for (int j = 0; j < 8; ++j) acc[j] = 0.f;

    const u16* vb = value + ((size_t)b * P_) * 256 + m * 32 + gq * 8;

    #pragma unroll
    for (int k = 0; k < 4; ++k) {
        const float offx = bf2f(ov[2 * k]), offy = bf2f(ov[2 * k + 1]);
        const float px = (float)(63 - x) + offx;
        const float py = (float)y + offy;
        const float x0f = floorf(px), y0f = floorf(py);
        const int xi0 = (int)x0f, yi0 = (int)y0f;
        const float wx = px - x0f, wy = py - y0f;
        const int xi1 = xi0 + 1, yi1 = yi0 + 1;
        const bool vx0 = (xi0 >= 0) & (xi0 <= 63), vx1 = (xi1 >= 0) & (xi1 <= 63);
        const bool vy0 = (yi0 >= 0) & (yi0 <= 63), vy1 = (yi1 >= 0) & (yi1 <= 63);
        const int cx0 = min(max(xi0, 0), 63), cx1 = min(max(xi1, 0), 63);
        const int cy0 = min(max(yi0, 0), 63), cy1 = min(max(yi1, 0), 63);
        const float ak = a[k] * inv;
        const float c00 = ak * (1.f - wx) * (1.f - wy) * ((vx0 & vy0) ? 1.f : 0.f);
        const float c01 = ak * wx * (1.f - wy) * ((vx1 & vy0) ? 1.f : 0.f);
        const float c10 = ak * (1.f - wx) * wy * ((vx0 & vy1) ? 1.f : 0.f);
        const float c11 = ak * wx * wy * ((vx1 & vy1) ? 1.f : 0.f);
        const u16x8 v00 = *(const u16x8*)&vb[(size_t)(cy0 * 64 + cx0) * 256];
        const u16x8 v01 = *(const u16x8*)&vb[(size_t)(cy0 * 64 + cx1) * 256];
        const u16x8 v10 = *(const u16x8*)&vb[(size_t)(cy1 * 64 + cx0) * 256];
        const u16x8 v11 = *(const u16x8*)&vb[(size_t)(cy1 * 64 + cx1) * 256];
        #pragma unroll
        for (int j = 0; j < 8; ++j)
            acc[j] += c00 * bf2f(v00[j]) + c01 * bf2f(v01[j])
                    + c10 * bf2f(v10[j]) + c11 * bf2f(v11[j]);
    }
    u16x8 o;
    #pragma unroll
    for (int j = 0; j < 8; ++j) o[j] = f2bf(acc[j]);
    *(u16x8*)&out1[prow * 256 + m * 32 + gq * 8] = o;
}

// ---------------------------------------------------------------------------
extern "C" void kernel_launch(void* const* d_in, const int* in_sizes, int n_in,
                              void* d_out, int out_size, void* d_ws, size_t ws_size,
                              hipStream_t stream) {
    const float* f_recalib = (const float*)d_in[0];
    const float* f_orig    = (const float*)d_in[1];
    const float* offset_w  = (const float*)d_in[2];
    const float* offset_b  = (const float*)d_in[3];
    const float* attn_w    = (const float*)d_in[4];
    const float* attn_b    = (const float*)d_in[5];
    const float* value_w   = (const float*)d_in[6];
    const float* value_b   = (const float*)d_in[7];
    const float* proj_w    = (const float*)d_in[8];
    const float* proj_b    = (const float*)d_in[9];
    const float* mlp_w1    = (const float*)d_in[10];
    const float* mlp_b1    = (const float*)d_in[11];
    const float* mlp_w2    = (const float*)d_in[12];
    const float* mlp_b2    = (const float*)d_in[13];
    float* out = (float*)d_out;

    u16* wsb      = (u16*)d_ws;
    u16* x_bf     = wsb;                  // 8,388,608 u16 (16 MB)
    u16* convout  = wsb + 8388608;        // 3,145,728 (6 MB)
    u16* value_bf = wsb + 11534336;       // 8,388,608 (16 MB)
    u16* out1_bf  = wsb + 19922944;       // 8,388,608 (16 MB)
    u16* wbf      = wsb + 28311552;       // 614,400 (1.2 MB) -> 55.2 MB total
    u16* out2_bf  = x_bf;                 // alias: x_bf dead after value GEMM
    u16* h_bf     = wsb + 8388608;        // alias convout..out1 (all dead), 32 MB

    u16* wconv = wbf;
    u16* wval  = wbf + 221184;
    u16* wproj = wbf + 286720;
    u16* wmlp1 = wbf + 352256;
    u16* wmlp2 = wbf + 483328;

    prep_weights<<<2400, 256, 0, stream>>>(offset_w, attn_w, value_w, proj_w,
                                           mlp_w1, mlp_w2, wbf);
    to_nhwc_bf16<<<dim3(64, 4, 8), 256, 0, stream>>>(f_recalib, x_bf, 256);
    conv3x3_mfma<<<dim3(64, 8), 256, 0, stream>>>(x_bf, wconv, offset_b, attn_b, convout);
    gemm_nhwc<<<dim3(64, 4, 8), 256, 0, stream>>>(x_bf, wval, value_b, nullptr,
                                                  value_bf, 256, 256, 0);
    sample_attend_bf<<<dim3(64, 8, 8), 256, 0, stream>>>(value_bf, convout, out1_bf);
    gemm_nhwc<<<dim3(64, 4, 8), 256, 0, stream>>>(out1_bf, wproj, proj_b, f_orig,
                                                  out, 256, 256, 2);
    to_nhwc_bf16<<<dim3(64, 4, 8), 256, 0, stream>>>(out, out2_bf, 256);
    gemm_nhwc<<<dim3(64, 8, 8), 256, 0, stream>>>(out2_bf, wmlp1, mlp_b1, nullptr,
                                                  h_bf, 256, 512, 1);
    gemm_nhwc<<<dim3(64, 4, 8), 256, 0, stream>>>(h_bf, wmlp2, mlp_b2, out,
                                                  out, 512, 256, 2);
}

// Round 3
// 228.875 us; speedup vs baseline: 3.8318x; 1.1586x over previous
//
#include <hip/hip_runtime.h>
#include <cstddef>

#define P_ 4096

using u16 = unsigned short;
typedef float f32x4 __attribute__((ext_vector_type(4)));
typedef u16   u16x8 __attribute__((ext_vector_type(8)));
typedef u16   u16x4 __attribute__((ext_vector_type(4)));

#define DEVINL __device__ __forceinline__

DEVINL u16 f2bf(float f) {
    union { float f; unsigned u; } v; v.f = f;
    unsigned r = v.u + 0x7fffu + ((v.u >> 16) & 1u);
    return (u16)(r >> 16);
}
DEVINL float bf2f(u16 h) {
    union { unsigned u; float f; } v; v.u = ((unsigned)h) << 16;
    return v.f;
}

DEVINL f32x4 mfma16(u16x8 a, u16x8 b, f32x4 c) {
    asm volatile("v_mfma_f32_16x16x32_bf16 %0, %1, %2, %0"
                 : "+v"(c) : "v"(a), "v"(b));
    return c;
}

DEVINL void gload16(const u16* src, const u16* lds_dst) {
    __builtin_amdgcn_global_load_lds(
        (const __attribute__((address_space(1))) void*)src,
        (__attribute__((address_space(3))) void*)lds_dst, 16, 0, 0);
}

// ---------------------------------------------------------------------------
// prep_weights: all weights -> bf16. conv weights reordered to [tap][96][256].
// ---------------------------------------------------------------------------
__global__ void prep_weights(const float* __restrict__ off_w, const float* __restrict__ attn_w,
                             const float* __restrict__ val_w, const float* __restrict__ proj_w,
                             const float* __restrict__ w1, const float* __restrict__ w2,
                             u16* __restrict__ wbf) {
    int idx = blockIdx.x * 256 + threadIdx.x;
    if (idx >= 614400) return;
    float v;
    if (idx < 221184) {
        int tap = idx / 24576, rem = idx - tap * 24576, oc = rem >> 8, ic = rem & 255;
        v = (oc < 64) ? off_w[(size_t)(oc * 256 + ic) * 9 + tap]
                      : attn_w[(size_t)((oc - 64) * 256 + ic) * 9 + tap];
    } else if (idx < 286720) v = val_w[idx - 221184];
    else if (idx < 352256)   v = proj_w[idx - 286720];
    else if (idx < 483328)   v = w1[idx - 352256];
    else                     v = w2[idx - 483328];
    wbf[idx] = f2bf(v);
}

// ---------------------------------------------------------------------------
// NCHW fp32 -> NHWC bf16 (LDS-tiled transpose). grid (64, C/64, B), 256 thr.
// ---------------------------------------------------------------------------
__global__ __launch_bounds__(256) void to_nhwc_bf16(const float* __restrict__ in,
                                                    u16* __restrict__ out, int C) {
    const int px0 = blockIdx.x * 64, c0 = blockIdx.y * 64, b = blockIdx.z;
    __shared__ u16 ts[64 * 72];
    const int t = threadIdx.x, cl = t >> 4, xq = t & 15;
    #pragma unroll
    for (int r = 0; r < 4; ++r) {
        const int c = r * 16 + cl;
        const float4 v = *(const float4*)&in[((size_t)(b * C + c0 + c)) * P_ + px0 + xq * 4];
        ts[(xq * 4 + 0) * 72 + c] = f2bf(v.x);
        ts[(xq * 4 + 1) * 72 + c] = f2bf(v.y);
        ts[(xq * 4 + 2) * 72 + c] = f2bf(v.z);
        ts[(xq * 4 + 3) * 72 + c] = f2bf(v.w);
    }
    __syncthreads();
    const int px = t >> 2, seg = t & 3;
    u16x8 o0, o1;
    #pragma unroll
    for (int j = 0; j < 8; ++j) {
        o0[j] = ts[px * 72 + seg * 16 + j];
        o1[j] = ts[px * 72 + seg * 16 + 8 + j];
    }
    const size_t base = ((size_t)(b * P_ + px0 + px)) * C + c0 + seg * 16;
    *(u16x8*)&out[base]     = o0;
    *(u16x8*)&out[base + 8] = o1;
}

// ---------------------------------------------------------------------------
// conv3x3 as 9 shifted-tap MFMA GEMMs. grid (64 y, 8 b), 256 thr (4 waves).
// LDS: only the x-tile, 3 rows x 66 slots x 64ic (guard cols at x=-1,64 so
// shifted A-reads need no masking). Weights read directly from global (L2).
// Waves: wm=w&1 -> 32-px half, wn=w>>1 -> 48-oc half. acc[2 mi][3 nj].
// ---------------------------------------------------------------------------
__global__ __launch_bounds__(256) void conv3x3_mfma(
    const u16* __restrict__ xbf, const u16* __restrict__ wconv,
    const float* __restrict__ off_b, const float* __restrict__ attn_b,
    u16* __restrict__ convout) {
    const int y = blockIdx.x, b = blockIdx.y;
    const int tid = threadIdx.x, w = tid >> 6, lane = tid & 63, g = lane >> 4, i = lane & 15;
    const int wm = w & 1, wn = w >> 1;
    __shared__ u16 xs[3 * 66 * 64];    // [row r][slot 0..65][64 ic], slot = x+1

    f32x4 acc[2][3];
    #pragma unroll
    for (int mi = 0; mi < 2; ++mi)
        #pragma unroll
        for (int nj = 0; nj < 3; ++nj) acc[mi][nj] = (f32x4){0.f, 0.f, 0.f, 0.f};

    // zero guard slots (slot 0 and 65 of each row), once
    if (tid < 48) {
        const int r = tid >> 4, q = tid & 15;
        const int slot = (q < 8) ? 0 : 65, c = q & 7;
        *(u16x8*)&xs[(r * 66 + slot) * 64 + c * 8] = (u16x8){0, 0, 0, 0, 0, 0, 0, 0};
    }

    // per-lane A-read element offsets within a row: [mi][dx][ks]
    int aoff[2][3][2];
    #pragma unroll
    for (int mi = 0; mi < 2; ++mi)
        #pragma unroll
        for (int dx = 0; dx < 3; ++dx)
            #pragma unroll
            for (int ks = 0; ks < 2; ++ks) {
                const int x = (wm * 2 + mi) * 16 + i;
                const int slot = x + dx;            // (x+dx-1)+1
                aoff[mi][dx][ks] = slot * 64 + (((ks * 4 + g) ^ (slot & 7)) << 3);
            }

    for (int cc = 0; cc < 4; ++cc) {
        const int ic0 = cc * 64;
        #pragma unroll
        for (int r = 0; r < 3; ++r) {
            const int yy = y + r - 1;
            if ((unsigned)yy < 64u) {
                #pragma unroll
                for (int t = 0; t < 2; ++t) {
                    const int ii = w * 2 + t;                    // 0..7
                    const int px = ii * 8 + (lane >> 3), c = lane & 7;
                    const u16* src = xbf + (((size_t)(b * P_ + yy * 64 + px)) << 8) + ic0
                                     + ((c ^ ((px + 1) & 7)) << 3);
                    gload16(src, &xs[(r * 66 + ii * 8 + 1) * 64]);
                }
            }
        }
        __syncthreads();
        const u16* wc = wconv + ic0;
        #pragma unroll
        for (int tap = 0; tap < 9; ++tap) {
            const int dy = tap / 3, dx = tap % 3;
            const int yy = y + dy - 1;
            if ((unsigned)yy >= 64u) continue;
            #pragma unroll
            for (int ks = 0; ks < 2; ++ks) {
                const u16x8 a0 = *(const u16x8*)&xs[dy * 4224 + aoff[0][dx][ks]];
                const u16x8 a1 = *(const u16x8*)&xs[dy * 4224 + aoff[1][dx][ks]];
                #pragma unroll
                for (int nj = 0; nj < 3; ++nj) {
                    const int oc = (wn * 3 + nj) * 16 + i;
                    const u16x8 bb = *(const u16x8*)&wc[(((size_t)(tap * 96 + oc)) << 8)
                                                        + ks * 32 + g * 8];
                    acc[0][nj] = mfma16(a0, bb, acc[0][nj]);
                    acc[1][nj] = mfma16(a1, bb, acc[1][nj]);
                }
            }
        }
        __syncthreads();
    }
    asm volatile("s_nop 7\n\ts_nop 7" :::);
    #pragma unroll
    for (int mi = 0; mi < 2; ++mi) {
        const int x0 = (wm * 2 + mi) * 16 + g * 4;
        #pragma unroll
        for (int nj = 0; nj < 3; ++nj) {
            const int oc = (wn * 3 + nj) * 16 + i;
            const float bv = (oc < 64) ? off_b[oc] : attn_b[oc - 64];
            #pragma unroll
            for (int r = 0; r < 4; ++r)
                convout[((size_t)(b * P_ + y * 64 + x0 + r)) * 96 + oc] =
                    f2bf(acc[mi][nj][r] + bv);
        }
    }
}

// ---------------------------------------------------------------------------
// NHWC bf16 MFMA GEMM: out[px][oc] = sum_k X[px][k] * W[oc][k]  (per batch)
// mode 0: +bias -> bf16 NHWC; mode 1: +bias,relu -> bf16 NHWC;
// mode 2: +bias +resid(NCHW f32) -> f32 NCHW (LDS transpose epilogue).
// ---------------------------------------------------------------------------
__global__ __launch_bounds__(256) void gemm_nhwc(
    const u16* __restrict__ X, const u16* __restrict__ W,
    const float* __restrict__ bias, const float* __restrict__ resid,
    void* __restrict__ outp, const int KTOT, const int OC, const int mode) {
    const int px0 = blockIdx.x * 64, oc0 = blockIdx.y * 64, b = blockIdx.z;
    const int tid = threadIdx.x, w = tid >> 6, lane = tid & 63, g = lane >> 4, i = lane & 15;
    const int wm = (w & 1) * 2, wn = (w >> 1) * 2;
    __shared__ u16 xs[64 * 256];     // [px][256k] swizzled 16B chunks
    __shared__ u16 wsL[64 * 264];    // [oc][264 pad]

    f32x4 acc[2][2];
    #pragma unroll
    for (int mi = 0; mi < 2; ++mi)
        #pragma unroll
        for (int nj = 0; nj < 2; ++nj) acc[mi][nj] = (f32x4){0.f, 0.f, 0.f, 0.f};

    for (int kc = 0; kc < KTOT; kc += 256) {
        for (int ii = w; ii < 32; ii += 4) {
            const int px = ii * 2 + (lane >> 5), c = lane & 31;
            const u16* src = X + ((size_t)(b * P_ + px0 + px)) * KTOT + kc
                             + ((c ^ (px & 7)) << 3);
            gload16(src, &xs[ii * 512]);
        }
        for (int q = tid; q < 2048; q += 256) {
            const int oc = q >> 5, c = q & 31;
            const u16x8 v = *(const u16x8*)&W[(size_t)(oc0 + oc) * KTOT + kc + (c << 3)];
            *(u16x8*)&wsL[oc * 264 + (c << 3)] = v;
        }
        __syncthreads();
        #pragma unroll
        for (int ks = 0; ks < 8; ++ks) {
            u16x8 a[2], bb[2];
            #pragma unroll
            for (int mi = 0; mi < 2; ++mi) {
                const int px = (wm + mi) * 16 + i;
                a[mi] = *(const u16x8*)&xs[px * 256 + (((ks * 4 + g) ^ (px & 7)) << 3)];
            }
            #pragma unroll
            for (int nj = 0; nj < 2; ++nj)
                bb[nj] = *(const u16x8*)&wsL[((wn + nj) * 16 + i) * 264 + ((ks * 4 + g) << 3)];
            acc[0][0] = mfma16(a[0], bb[0], acc[0][0]);
            acc[1][0] = mfma16(a[1], bb[0], acc[1][0]);
            acc[0][1] = mfma16(a[0], bb[1], acc[0][1]);
            acc[1][1] = mfma16(a[1], bb[1], acc[1][1]);
        }
        __syncthreads();
    }
    asm volatile("s_nop 7\n\ts_nop 7" :::);

    if (mode < 2) {
        u16* out = (u16*)outp;
        #pragma unroll
        for (int mi = 0; mi < 2; ++mi) {
            #pragma unroll
            for (int nj = 0; nj < 2; ++nj) {
                const int ocg = oc0 + (wn + nj) * 16 + i;
                const float bv = bias[ocg];
                #pragma unroll
                for (int r = 0; r < 4; ++r) {
                    const int px = px0 + (wm + mi) * 16 + g * 4 + r;
                    float v = acc[mi][nj][r] + bv;
                    if (mode == 1) v = fmaxf(v, 0.f);
                    out[((size_t)(b * P_ + px)) * OC + ocg] = f2bf(v);
                }
            }
        }
    } else {
        float* lf = (float*)xs;   // 64 x 68 f32 = 17408 B, fits in xs
        #pragma unroll
        for (int mi = 0; mi < 2; ++mi) {
            #pragma unroll
            for (int nj = 0; nj < 2; ++nj) {
                const int ocl = (wn + nj) * 16 + i;
                const float bv = bias[oc0 + ocl];
                #pragma unroll
                for (int r = 0; r < 4; ++r) {
                    const int pxl = (wm + mi) * 16 + g * 4 + r;
                    lf[ocl * 68 + pxl] = acc[mi][nj][r] + bv;
                }
            }
        }
        __syncthreads();
        float* out = (float*)outp;
        const int ocl = tid >> 2, pq = (tid & 3) * 16;
        const size_t base = ((size_t)b * OC + oc0 + ocl) * P_ + px0 + pq;
        #pragma unroll
        for (int jq = 0; jq < 4; ++jq) {
            const float4 r4 = *(const float4*)&resid[base + jq * 4];
            float4 o;
            o.x = lf[ocl * 68 + pq + jq * 4 + 0] + r4.x;
            o.y = lf[ocl * 68 + pq + jq * 4 + 1] + r4.y;
            o.z = lf[ocl * 68 + pq + jq * 4 + 2] + r4.z;
            o.w = lf[ocl * 68 + pq + jq * 4 + 3] + r4.w;
            *(float4*)&out[base + jq * 4] = o;
        }
    }
}

// ---------------------------------------------------------------------------
// softmax over K + bilinear grid-sample + weighted sum. NHWC bf16 in/out.
// ---------------------------------------------------------------------------
__global__ __launch_bounds__(256) void sample_attend_bf(
    const u16* __restrict__ value, const u16* __restrict__ conv,
    u16* __restrict__ out1) {
    const int y = blockIdx.x, m = blockIdx.y, b = blockIdx.z;
    const int tid = threadIdx.x, x = tid >> 2, gq = tid & 3;
    const size_t prow = (size_t)(b * P_ + y * 64 + x);

    const u16x8 ov = *(const u16x8*)&conv[prow * 96 + m * 8];
    const u16x4 av = *(const u16x4*)&conv[prow * 96 + 64 + m * 4];

    float a[4];
    #pragma unroll
    for (int k = 0; k < 4; ++k) a[k] = bf2f(av[k]);
    const float mx = fmaxf(fmaxf(a[0], a[1]), fmaxf(a[2], a[3]));
    float s = 0.f;
    #pragma unroll
    for (int k = 0; k < 4; ++k) { a[k] = __expf(a[k] - mx); s += a[k]; }
    const float inv = 1.f / s;

    float acc[8];
    #pragma unroll
    for (int j = 0; j < 8; ++j) acc[j] = 0.f;

    const u16* vb = value + ((size_t)b * P_) * 256 + m * 32 + gq * 8;

    #pragma unroll
    for (int k = 0; k < 4; ++k) {
        const float offx = bf2f(ov[2 * k]), offy = bf2f(ov[2 * k + 1]);
        const float px = (float)(63 - x) + offx;
        const float py = (float)y + offy;
        const float x0f = floorf(px), y0f = floorf(py);
        const int xi0 = (int)x0f, yi0 = (int)y0f;
        const float wx = px - x0f, wy = py - y0f;
        const int xi1 = xi0 + 1, yi1 = yi0 + 1;
        const bool vx0 = (xi0 >= 0) & (xi0 <= 63), vx1 = (xi1 >= 0) & (xi1 <= 63);
        const bool vy0 = (yi0 >= 0) & (yi0 <= 63), vy1 = (yi1 >= 0) & (yi1 <= 63);
        const int cx0 = min(max(xi0, 0), 63), cx1 = min(max(xi1, 0), 63);
        const int cy0 = min(max(yi0, 0), 63), cy1 = min(max(yi1, 0), 63);
        const float ak = a[k] * inv;
        const float c00 = ak * (1.f - wx) * (1.f - wy) * ((vx0 & vy0) ? 1.f : 0.f);
        const float c01 = ak * wx * (1.f - wy) * ((vx1 & vy0) ? 1.f : 0.f);
        const float c10 = ak * (1.f - wx) * wy * ((vx0 & vy1) ? 1.f : 0.f);
        const float c11 = ak * wx * wy * ((vx1 & vy1) ? 1.f : 0.f);
        const u16x8 v00 = *(const u16x8*)&vb[(size_t)(cy0 * 64 + cx0) * 256];
        const u16x8 v01 = *(const u16x8*)&vb[(size_t)(cy0 * 64 + cx1) * 256];
        const u16x8 v10 = *(const u16x8*)&vb[(size_t)(cy1 * 64 + cx0) * 256];
        const u16x8 v11 = *(const u16x8*)&vb[(size_t)(cy1 * 64 + cx1) * 256];
        #pragma unroll
        for (int j = 0; j < 8; ++j)
            acc[j] += c00 * bf2f(v00[j]) + c01 * bf2f(v01[j])
                    + c10 * bf2f(v10[j]) + c11 * bf2f(v11[j]);
    }
    u16x8 o;
    #pragma unroll
    for (int j = 0; j < 8; ++j) o[j] = f2bf(acc[j]);
    *(u16x8*)&out1[prow * 256 + m * 32 + gq * 8] = o;
}

// ---------------------------------------------------------------------------
extern "C" void kernel_launch(void* const* d_in, const int* in_sizes, int n_in,
                              void* d_out, int out_size, void* d_ws, size_t ws_size,
                              hipStream_t stream) {
    const float* f_recalib = (const float*)d_in[0];
    const float* f_orig    = (const float*)d_in[1];
    const float* offset_w  = (const float*)d_in[2];
    const float* offset_b  = (const float*)d_in[3];
    const float* attn_w    = (const float*)d_in[4];
    const float* attn_b    = (const float*)d_in[5];
    const float* value_w   = (const float*)d_in[6];
    const float* value_b   = (const float*)d_in[7];
    const float* proj_w    = (const float*)d_in[8];
    const float* proj_b    = (const float*)d_in[9];
    const float* mlp_w1    = (const float*)d_in[10];
    const float* mlp_b1    = (const float*)d_in[11];
    const float* mlp_w2    = (const float*)d_in[12];
    const float* mlp_b2    = (const float*)d_in[13];
    float* out = (float*)d_out;

    u16* wsb      = (u16*)d_ws;
    u16* x_bf     = wsb;                  // 8,388,608 u16 (16 MB)
    u16* convout  = wsb + 8388608;        // 3,145,728 (6 MB)
    u16* value_bf = wsb + 11534336;       // 8,388,608 (16 MB)
    u16* out1_bf  = wsb + 19922944;       // 8,388,608 (16 MB)
    u16* wbf      = wsb + 28311552;       // 614,400 (1.2 MB) -> 55.2 MB total
    u16* out2_bf  = x_bf;                 // alias: x_bf dead after value GEMM+conv
    u16* h_bf     = wsb + 8388608;        // alias convout..out1 (all dead), 32 MB

    u16* wconv = wbf;
    u16* wval  = wbf + 221184;
    u16* wproj = wbf + 286720;
    u16* wmlp1 = wbf + 352256;
    u16* wmlp2 = wbf + 483328;

    prep_weights<<<2400, 256, 0, stream>>>(offset_w, attn_w, value_w, proj_w,
                                           mlp_w1, mlp_w2, wbf);
    to_nhwc_bf16<<<dim3(64, 4, 8), 256, 0, stream>>>(f_recalib, x_bf, 256);
    conv3x3_mfma<<<dim3(64, 8), 256, 0, stream>>>(x_bf, wconv, offset_b, attn_b, convout);
    gemm_nhwc<<<dim3(64, 4, 8), 256, 0, stream>>>(x_bf, wval, value_b, nullptr,
                                                  value_bf, 256, 256, 0);
    sample_attend_bf<<<dim3(64, 8, 8), 256, 0, stream>>>(value_bf, convout, out1_bf);
    gemm_nhwc<<<dim3(64, 4, 8), 256, 0, stream>>>(out1_bf, wproj, proj_b, f_orig,
                                                  out, 256, 256, 2);
    to_nhwc_bf16<<<dim3(64, 4, 8), 256, 0, stream>>>(out, out2_bf, 256);
    gemm_nhwc<<<dim3(64, 8, 8), 256, 0, stream>>>(out2_bf, wmlp1, mlp_b1, nullptr,
                                                  h_bf, 256, 512, 1);
    gemm_nhwc<<<dim3(64, 4, 8), 256, 0, stream>>>(h_bf, wmlp2, mlp_b2, out,
                                                  out, 512, 256, 2);
}

// Round 4
// 228.200 us; speedup vs baseline: 3.8431x; 1.0030x over previous
//
#include <hip/hip_runtime.h>
#include <cstddef>

#define P_ 4096

using u16 = unsigned short;
typedef float  f32x4  __attribute__((ext_vector_type(4)));
typedef u16    u16x8  __attribute__((ext_vector_type(8)));
typedef u16    u16x4  __attribute__((ext_vector_type(4)));
typedef __bf16 bf16x8 __attribute__((ext_vector_type(8)));

#define DEVINL __device__ __forceinline__

DEVINL u16 f2bf(float f) {
    union { float f; unsigned u; } v; v.f = f;
    unsigned r = v.u + 0x7fffu + ((v.u >> 16) & 1u);
    return (u16)(r >> 16);
}
DEVINL float bf2f(u16 h) {
    union { unsigned u; float f; } v; v.u = ((unsigned)h) << 16;
    return v.f;
}

DEVINL f32x4 mfma16(u16x8 a, u16x8 b, f32x4 c) {
    return __builtin_amdgcn_mfma_f32_16x16x32_bf16(
        __builtin_bit_cast(bf16x8, a), __builtin_bit_cast(bf16x8, b), c, 0, 0, 0);
}

DEVINL void gload16(const u16* src, const u16* lds_dst) {
    __builtin_amdgcn_global_load_lds(
        (const __attribute__((address_space(1))) void*)src,
        (__attribute__((address_space(3))) void*)lds_dst, 16, 0, 0);
}

// ---------------------------------------------------------------------------
// prep_weights: all weights -> bf16. conv weights reordered to [tap][96][256].
// ---------------------------------------------------------------------------
__global__ void prep_weights(const float* __restrict__ off_w, const float* __restrict__ attn_w,
                             const float* __restrict__ val_w, const float* __restrict__ proj_w,
                             const float* __restrict__ w1, const float* __restrict__ w2,
                             u16* __restrict__ wbf) {
    int idx = blockIdx.x * 256 + threadIdx.x;
    if (idx >= 614400) return;
    float v;
    if (idx < 221184) {
        int tap = idx / 24576, rem = idx - tap * 24576, oc = rem >> 8, ic = rem & 255;
        v = (oc < 64) ? off_w[(size_t)(oc * 256 + ic) * 9 + tap]
                      : attn_w[(size_t)((oc - 64) * 256 + ic) * 9 + tap];
    } else if (idx < 286720) v = val_w[idx - 221184];
    else if (idx < 352256)   v = proj_w[idx - 286720];
    else if (idx < 483328)   v = w1[idx - 352256];
    else                     v = w2[idx - 483328];
    wbf[idx] = f2bf(v);
}

// ---------------------------------------------------------------------------
// NCHW fp32 -> NHWC bf16 (LDS-tiled transpose). grid (64, C/64, B), 256 thr.
// ---------------------------------------------------------------------------
__global__ __launch_bounds__(256) void to_nhwc_bf16(const float* __restrict__ in,
                                                    u16* __restrict__ out, int C) {
    const int px0 = blockIdx.x * 64, c0 = blockIdx.y * 64, b = blockIdx.z;
    __shared__ u16 ts[64 * 72];
    const int t = threadIdx.x, cl = t >> 4, xq = t & 15;
    #pragma unroll
    for (int r = 0; r < 4; ++r) {
        const int c = r * 16 + cl;
        const float4 v = *(const float4*)&in[((size_t)(b * C + c0 + c)) * P_ + px0 + xq * 4];
        ts[(xq * 4 + 0) * 72 + c] = f2bf(v.x);
        ts[(xq * 4 + 1) * 72 + c] = f2bf(v.y);
        ts[(xq * 4 + 2) * 72 + c] = f2bf(v.z);
        ts[(xq * 4 + 3) * 72 + c] = f2bf(v.w);
    }
    __syncthreads();
    const int px = t >> 2, seg = t & 3;
    u16x8 o0, o1;
    #pragma unroll
    for (int j = 0; j < 8; ++j) {
        o0[j] = ts[px * 72 + seg * 16 + j];
        o1[j] = ts[px * 72 + seg * 16 + 8 + j];
    }
    const size_t base = ((size_t)(b * P_ + px0 + px)) * C + c0 + seg * 16;
    *(u16x8*)&out[base]     = o0;
    *(u16x8*)&out[base + 8] = o1;
}

// ---------------------------------------------------------------------------
// conv3x3 as 9 shifted-tap MFMA GEMMs. grid (64 y, 8 b), 256 thr (4 waves).
// LDS: only the x-tile, 3 rows x 66 slots x 64ic (guard cols at x=-1,64).
// Weights read directly from global (L2). acc[2 mi][3 nj] per wave.
// ---------------------------------------------------------------------------
__global__ __launch_bounds__(256, 2) void conv3x3_mfma(
    const u16* __restrict__ xbf, const u16* __restrict__ wconv,
    const float* __restrict__ off_b, const float* __restrict__ attn_b,
    u16* __restrict__ convout) {
    const int y = blockIdx.x, b = blockIdx.y;
    const int tid = threadIdx.x, w = tid >> 6, lane = tid & 63, g = lane >> 4, i = lane & 15;
    const int wm = w & 1, wn = w >> 1;
    __shared__ u16 xs[3 * 66 * 64];    // [row r][slot 0..65][64 ic], slot = x+1

    f32x4 acc[2][3];
    #pragma unroll
    for (int mi = 0; mi < 2; ++mi)
        #pragma unroll
        for (int nj = 0; nj < 3; ++nj) acc[mi][nj] = (f32x4){0.f, 0.f, 0.f, 0.f};

    // zero guard slots (slot 0 and 65 of each row), once
    if (tid < 48) {
        const int r = tid >> 4, q = tid & 15;
        const int slot = (q < 8) ? 0 : 65, c = q & 7;
        *(u16x8*)&xs[(r * 66 + slot) * 64 + c * 8] = (u16x8){0, 0, 0, 0, 0, 0, 0, 0};
    }

    // per-lane A-read element offsets within a row: [mi][dx][ks]
    int aoff[2][3][2];
    #pragma unroll
    for (int mi = 0; mi < 2; ++mi)
        #pragma unroll
        for (int dx = 0; dx < 3; ++dx)
            #pragma unroll
            for (int ks = 0; ks < 2; ++ks) {
                const int x = (wm * 2 + mi) * 16 + i;
                const int slot = x + dx;            // (x+dx-1)+1
                aoff[mi][dx][ks] = slot * 64 + (((ks * 4 + g) ^ (slot & 7)) << 3);
            }

    for (int cc = 0; cc < 4; ++cc) {
        const int ic0 = cc * 64;
        #pragma unroll
        for (int r = 0; r < 3; ++r) {
            const int yy = y + r - 1;
            if ((unsigned)yy < 64u) {
                #pragma unroll
                for (int t = 0; t < 2; ++t) {
                    const int ii = w * 2 + t;                    // 0..7
                    const int px = ii * 8 + (lane >> 3), c = lane & 7;
                    const u16* src = xbf + (((size_t)(b * P_ + yy * 64 + px)) << 8) + ic0
                                     + ((c ^ ((px + 1) & 7)) << 3);
                    gload16(src, &xs[(r * 66 + ii * 8 + 1) * 64]);
                }
            }
        }
        __syncthreads();
        const u16* wc = wconv + ic0;
        #pragma unroll
        for (int tap = 0; tap < 9; ++tap) {
            const int dy = tap / 3, dx = tap % 3;
            const int yy = y + dy - 1;
            if ((unsigned)yy >= 64u) continue;
            #pragma unroll
            for (int ks = 0; ks < 2; ++ks) {
                const u16x8 a0 = *(const u16x8*)&xs[dy * 4224 + aoff[0][dx][ks]];
                const u16x8 a1 = *(const u16x8*)&xs[dy * 4224 + aoff[1][dx][ks]];
                #pragma unroll
                for (int nj = 0; nj < 3; ++nj) {
                    const int oc = (wn * 3 + nj) * 16 + i;
                    const u16x8 bb = *(const u16x8*)&wc[(((size_t)(tap * 96 + oc)) << 8)
                                                        + ks * 32 + g * 8];
                    acc[0][nj] = mfma16(a0, bb, acc[0][nj]);
                    acc[1][nj] = mfma16(a1, bb, acc[1][nj]);
                }
            }
        }
        __syncthreads();
    }
    #pragma unroll
    for (int mi = 0; mi < 2; ++mi) {
        const int x0 = (wm * 2 + mi) * 16 + g * 4;
        #pragma unroll
        for (int nj = 0; nj < 3; ++nj) {
            const int oc = (wn * 3 + nj) * 16 + i;
            const float bv = (oc < 64) ? off_b[oc] : attn_b[oc - 64];
            #pragma unroll
            for (int r = 0; r < 4; ++r)
                convout[((size_t)(b * P_ + y * 64 + x0 + r)) * 96 + oc] =
                    f2bf(acc[mi][nj][r] + bv);
        }
    }
}

// ---------------------------------------------------------------------------
// NHWC bf16 MFMA GEMM: out[px][oc] = sum_k X[px][k] * W[oc][k]  (per batch)
// mode 0: +bias -> bf16 NHWC; mode 1: +bias,relu -> bf16 NHWC;
// mode 2: +bias +resid(NCHW f32) -> f32 NCHW;
// mode 3: mode 2 AND bf16 NHWC copy of the result to out_nhwc.
// ---------------------------------------------------------------------------
__global__ __launch_bounds__(256, 2) void gemm_nhwc(
    const u16* __restrict__ X, const u16* __restrict__ W,
    const float* __restrict__ bias, const float* __restrict__ resid,
    void* __restrict__ outp, u16* __restrict__ out_nhwc,
    const int KTOT, const int OC, const int mode) {
    const int px0 = blockIdx.x * 64, oc0 = blockIdx.y * 64, b = blockIdx.z;
    const int tid = threadIdx.x, w = tid >> 6, lane = tid & 63, g = lane >> 4, i = lane & 15;
    const int wm = (w & 1) * 2, wn = (w >> 1) * 2;
    __shared__ u16 xs[64 * 256];     // [px][256k] swizzled 16B chunks
    __shared__ u16 wsL[64 * 264];    // [oc][264 pad]

    f32x4 acc[2][2];
    #pragma unroll
    for (int mi = 0; mi < 2; ++mi)
        #pragma unroll
        for (int nj = 0; nj < 2; ++nj) acc[mi][nj] = (f32x4){0.f, 0.f, 0.f, 0.f};

    for (int kc = 0; kc < KTOT; kc += 256) {
        for (int ii = w; ii < 32; ii += 4) {
            const int px = ii * 2 + (lane >> 5), c = lane & 31;
            const u16* src = X + ((size_t)(b * P_ + px0 + px)) * KTOT + kc
                             + ((c ^ (px & 7)) << 3);
            gload16(src, &xs[ii * 512]);
        }
        for (int q = tid; q < 2048; q += 256) {
            const int oc = q >> 5, c = q & 31;
            const u16x8 v = *(const u16x8*)&W[(size_t)(oc0 + oc) * KTOT + kc + (c << 3)];
            *(u16x8*)&wsL[oc * 264 + (c << 3)] = v;
        }
        __syncthreads();
        #pragma unroll
        for (int ks = 0; ks < 8; ++ks) {
            u16x8 a[2], bb[2];
            #pragma unroll
            for (int mi = 0; mi < 2; ++mi) {
                const int px = (wm + mi) * 16 + i;
                a[mi] = *(const u16x8*)&xs[px * 256 + (((ks * 4 + g) ^ (px & 7)) << 3)];
            }
            #pragma unroll
            for (int nj = 0; nj < 2; ++nj)
                bb[nj] = *(const u16x8*)&wsL[((wn + nj) * 16 + i) * 264 + ((ks * 4 + g) << 3)];
            acc[0][0] = mfma16(a[0], bb[0], acc[0][0]);
            acc[1][0] = mfma16(a[1], bb[0], acc[1][0]);
            acc[0][1] = mfma16(a[0], bb[1], acc[0][1]);
            acc[1][1] = mfma16(a[1], bb[1], acc[1][1]);
        }
        __syncthreads();
    }

    if (mode < 2) {
        u16* out = (u16*)outp;
        #pragma unroll
        for (int mi = 0; mi < 2; ++mi) {
            #pragma unroll
            for (int nj = 0; nj < 2; ++nj) {
                const int ocg = oc0 + (wn + nj) * 16 + i;
                const float bv = bias[ocg];
                #pragma unroll
                for (int r = 0; r < 4; ++r) {
                    const int px = px0 + (wm + mi) * 16 + g * 4 + r;
                    float v = acc[mi][nj][r] + bv;
                    if (mode == 1) v = fmaxf(v, 0.f);
                    out[((size_t)(b * P_ + px)) * OC + ocg] = f2bf(v);
                }
            }
        }
    } else {
        float* lf = (float*)xs;   // 64 oc x 68 px f32 = 17408 B, fits in xs
        #pragma unroll
        for (int mi = 0; mi < 2; ++mi) {
            #pragma unroll
            for (int nj = 0; nj < 2; ++nj) {
                const int ocl = (wn + nj) * 16 + i;
                const float bv = bias[oc0 + ocl];
                #pragma unroll
                for (int r = 0; r < 4; ++r) {
                    const int pxl = (wm + mi) * 16 + g * 4 + r;
                    lf[ocl * 68 + pxl] = acc[mi][nj][r] + bv;
                }
            }
        }
        __syncthreads();
        float* out = (float*)outp;
        const int ocl = tid >> 2, pq = (tid & 3) * 16;
        const size_t base = ((size_t)b * OC + oc0 + ocl) * P_ + px0 + pq;
        #pragma unroll
        for (int jq = 0; jq < 4; ++jq) {
            const float4 r4 = *(const float4*)&resid[base + jq * 4];
            float4 o;
            o.x = lf[ocl * 68 + pq + jq * 4 + 0] + r4.x;
            o.y = lf[ocl * 68 + pq + jq * 4 + 1] + r4.y;
            o.z = lf[ocl * 68 + pq + jq * 4 + 2] + r4.z;
            o.w = lf[ocl * 68 + pq + jq * 4 + 3] + r4.w;
            *(float4*)&out[base + jq * 4] = o;
            if (mode == 3) *(float4*)&lf[ocl * 68 + pq + jq * 4] = o;  // resid-added back
        }
        if (mode == 3) {
            __syncthreads();
            const int pxl2 = tid >> 2, seg = tid & 3;
            u16x8 o0, o1;
            #pragma unroll
            for (int j = 0; j < 8; ++j) {
                o0[j] = f2bf(lf[(seg * 16 + j) * 68 + pxl2]);
                o1[j] = f2bf(lf[(seg * 16 + 8 + j) * 68 + pxl2]);
            }
            const size_t b2 = ((size_t)(b * P_ + px0 + pxl2)) * OC + oc0 + seg * 16;
            *(u16x8*)&out_nhwc[b2]     = o0;
            *(u16x8*)&out_nhwc[b2 + 8] = o1;
        }
    }
}

// ---------------------------------------------------------------------------
// softmax over K + bilinear grid-sample + weighted sum. NHWC bf16 in/out.
// ---------------------------------------------------------------------------
__global__ __launch_bounds__(256) void sample_attend_bf(
    const u16* __restrict__ value, const u16* __restrict__ conv,
    u16* __restrict__ out1) {
    const int y = blockIdx.x, m = blockIdx.y, b = blockIdx.z;
    const int tid = threadIdx.x, x = tid >> 2, gq = tid & 3;
    const size_t prow = (size_t)(b * P_ + y * 64 + x);

    const u16x8 ov = *(const u16x8*)&conv[prow * 96 + m * 8];
    const u16x4 av = *(const u16x4*)&conv[prow * 96 + 64 + m * 4];

    float a[4];
    #pragma unroll
    for (int k = 0; k < 4; ++k) a[k] = bf2f(av[k]);
    const float mx = fmaxf(fmaxf(a[0], a[1]), fmaxf(a[2], a[3]));
    float s = 0.f;
    #pragma unroll
    for (int k = 0; k < 4; ++k) { a[k] = __expf(a[k] - mx); s += a[k]; }
    const float inv = 1.f / s;

    float acc[8];
    #pragma unroll
    for (int j = 0; j < 8; ++j) acc[j] = 0.f;

    const u16* vb = value + ((size_t)b * P_) * 256 + m * 32 + gq * 8;

    #pragma unroll
    for (int k = 0; k < 4; ++k) {
        const float offx = bf2f(ov[2 * k]), offy = bf2f(ov[2 * k + 1]);
        const float px = (float)(63 - x) + offx;
        const float py = (float)y + offy;
        const float x0f = floorf(px), y0f = floorf(py);
        const int xi0 = (int)x0f, yi0 = (int)y0f;
        const float wx = px - x0f, wy = py - y0f;
        const int xi1 = xi0 + 1, yi1 = yi0 + 1;
        const bool vx0 = (xi0 >= 0) & (xi0 <= 63), vx1 = (xi1 >= 0) & (xi1 <= 63);
        const bool vy0 = (yi0 >= 0) & (yi0 <= 63), vy1 = (yi1 >= 0) & (yi1 <= 63);
        const int cx0 = min(max(xi0, 0), 63), cx1 = min(max(xi1, 0), 63);
        const int cy0 = min(max(yi0, 0), 63), cy1 = min(max(yi1, 0), 63);
        const float ak = a[k] * inv;
        const float c00 = ak * (1.f - wx) * (1.f - wy) * ((vx0 & vy0) ? 1.f : 0.f);
        const float c01 = ak * wx * (1.f - wy) * ((vx1 & vy0) ? 1.f : 0.f);
        const float c10 = ak * (1.f - wx) * wy * ((vx0 & vy1) ? 1.f : 0.f);
        const float c11 = ak * wx * wy * ((vx1 & vy1) ? 1.f : 0.f);
        const u16x8 v00 = *(const u16x8*)&vb[(size_t)(cy0 * 64 + cx0) * 256];
        const u16x8 v01 = *(const u16x8*)&vb[(size_t)(cy0 * 64 + cx1) * 256];
        const u16x8 v10 = *(const u16x8*)&vb[(size_t)(cy1 * 64 + cx0) * 256];
        const u16x8 v11 = *(const u16x8*)&vb[(size_t)(cy1 * 64 + cx1) * 256];
        #pragma unroll
        for (int j = 0; j < 8; ++j)
            acc[j] += c00 * bf2f(v00[j]) + c01 * bf2f(v01[j])
                    + c10 * bf2f(v10[j]) + c11 * bf2f(v11[j]);
    }
    u16x8 o;
    #pragma unroll
    for (int j = 0; j < 8; ++j) o[j] = f2bf(acc[j]);
    *(u16x8*)&out1[prow * 256 + m * 32 + gq * 8] = o;
}

// ---------------------------------------------------------------------------
extern "C" void kernel_launch(void* const* d_in, const int* in_sizes, int n_in,
                              void* d_out, int out_size, void* d_ws, size_t ws_size,
                              hipStream_t stream) {
    const float* f_recalib = (const float*)d_in[0];
    const float* f_orig    = (const float*)d_in[1];
    const float* offset_w  = (const float*)d_in[2];
    const float* offset_b  = (const float*)d_in[3];
    const float* attn_w    = (const float*)d_in[4];
    const float* attn_b    = (const float*)d_in[5];
    const float* value_w   = (const float*)d_in[6];
    const float* value_b   = (const float*)d_in[7];
    const float* proj_w    = (const float*)d_in[8];
    const float* proj_b    = (const float*)d_in[9];
    const float* mlp_w1    = (const float*)d_in[10];
    const float* mlp_b1    = (const float*)d_in[11];
    const float* mlp_w2    = (const float*)d_in[12];
    const float* mlp_b2    = (const float*)d_in[13];
    float* out = (float*)d_out;

    u16* wsb      = (u16*)d_ws;
    u16* x_bf     = wsb;                  // 8,388,608 u16 (16 MB)
    u16* convout  = wsb + 8388608;        // 3,145,728 (6 MB)
    u16* value_bf = wsb + 11534336;       // 8,388,608 (16 MB)
    u16* out1_bf  = wsb + 19922944;       // 8,388,608 (16 MB)
    u16* wbf      = wsb + 28311552;       // 614,400 (1.2 MB) -> 55.2 MB total
    u16* out2_bf  = x_bf;                 // alias: x_bf dead after value GEMM+conv
    u16* h_bf     = wsb + 8388608;        // alias convout..out1 (all dead), 32 MB

    u16* wconv = wbf;
    u16* wval  = wbf + 221184;
    u16* wproj = wbf + 286720;
    u16* wmlp1 = wbf + 352256;
    u16* wmlp2 = wbf + 483328;

    prep_weights<<<2400, 256, 0, stream>>>(offset_w, attn_w, value_w, proj_w,
                                           mlp_w1, mlp_w2, wbf);
    to_nhwc_bf16<<<dim3(64, 4, 8), 256, 0, stream>>>(f_recalib, x_bf, 256);
    conv3x3_mfma<<<dim3(64, 8), 256, 0, stream>>>(x_bf, wconv, offset_b, attn_b, convout);
    gemm_nhwc<<<dim3(64, 4, 8), 256, 0, stream>>>(x_bf, wval, value_b, nullptr,
                                                  value_bf, nullptr, 256, 256, 0);
    sample_attend_bf<<<dim3(64, 8, 8), 256, 0, stream>>>(value_bf, convout, out1_bf);
    // proj + f_orig -> d_out (f32 NCHW) AND out2_bf (bf16 NHWC), fused
    gemm_nhwc<<<dim3(64, 4, 8), 256, 0, stream>>>(out1_bf, wproj, proj_b, f_orig,
                                                  out, out2_bf, 256, 256, 3);
    gemm_nhwc<<<dim3(64, 8, 8), 256, 0, stream>>>(out2_bf, wmlp1, mlp_b1, nullptr,
                                                  h_bf, nullptr, 256, 512, 1);
    gemm_nhwc<<<dim3(64, 4, 8), 256, 0, stream>>>(h_bf, wmlp2, mlp_b2, out,
                                                  out, nullptr, 512, 256, 2);
}

// Round 6
// 194.687 us; speedup vs baseline: 4.5047x; 1.1721x over previous
//
#include <hip/hip_runtime.h>
#include <cstddef>

#define P_ 4096

using u16 = unsigned short;
typedef float  f32x4  __attribute__((ext_vector_type(4)));
typedef u16    u16x8  __attribute__((ext_vector_type(8)));
typedef u16    u16x4  __attribute__((ext_vector_type(4)));
typedef __bf16 bf16x8 __attribute__((ext_vector_type(8)));

#define DEVINL __device__ __forceinline__

DEVINL u16 f2bf(float f) {
    union { float f; unsigned u; } v; v.f = f;
    unsigned r = v.u + 0x7fffu + ((v.u >> 16) & 1u);
    return (u16)(r >> 16);
}
DEVINL float bf2f(u16 h) {
    union { unsigned u; float f; } v; v.u = ((unsigned)h) << 16;
    return v.f;
}

DEVINL f32x4 mfma16(u16x8 a, u16x8 b, f32x4 c) {
    return __builtin_amdgcn_mfma_f32_16x16x32_bf16(
        __builtin_bit_cast(bf16x8, a), __builtin_bit_cast(bf16x8, b), c, 0, 0, 0);
}

DEVINL void gload16(const u16* src, const u16* lds_dst) {
    __builtin_amdgcn_global_load_lds(
        (const __attribute__((address_space(1))) void*)src,
        (__attribute__((address_space(3))) void*)lds_dst, 16, 0, 0);
}

// ---------------------------------------------------------------------------
// prep_weights: all weights -> bf16. conv weights reordered to [tap][96][256].
// ---------------------------------------------------------------------------
__global__ void prep_weights(const float* __restrict__ off_w, const float* __restrict__ attn_w,
                             const float* __restrict__ val_w, const float* __restrict__ proj_w,
                             const float* __restrict__ w1, const float* __restrict__ w2,
                             u16* __restrict__ wbf) {
    int idx = blockIdx.x * 256 + threadIdx.x;
    if (idx >= 614400) return;
    float v;
    if (idx < 221184) {
        int tap = idx / 24576, rem = idx - tap * 24576, oc = rem >> 8, ic = rem & 255;
        v = (oc < 64) ? off_w[(size_t)(oc * 256 + ic) * 9 + tap]
                      : attn_w[(size_t)((oc - 64) * 256 + ic) * 9 + tap];
    } else if (idx < 286720) v = val_w[idx - 221184];
    else if (idx < 352256)   v = proj_w[idx - 286720];
    else if (idx < 483328)   v = w1[idx - 352256];
    else                     v = w2[idx - 483328];
    wbf[idx] = f2bf(v);
}

// ---------------------------------------------------------------------------
// NCHW fp32 -> NHWC bf16 (LDS-tiled transpose). grid (64, C/64, B), 256 thr.
// ---------------------------------------------------------------------------
__global__ __launch_bounds__(256) void to_nhwc_bf16(const float* __restrict__ in,
                                                    u16* __restrict__ out, int C) {
    const int px0 = blockIdx.x * 64, c0 = blockIdx.y * 64, b = blockIdx.z;
    __shared__ u16 ts[64 * 72];
    const int t = threadIdx.x, cl = t >> 4, xq = t & 15;
    #pragma unroll
    for (int r = 0; r < 4; ++r) {
        const int c = r * 16 + cl;
        const float4 v = *(const float4*)&in[((size_t)(b * C + c0 + c)) * P_ + px0 + xq * 4];
        ts[(xq * 4 + 0) * 72 + c] = f2bf(v.x);
        ts[(xq * 4 + 1) * 72 + c] = f2bf(v.y);
        ts[(xq * 4 + 2) * 72 + c] = f2bf(v.z);
        ts[(xq * 4 + 3) * 72 + c] = f2bf(v.w);
    }
    __syncthreads();
    const int px = t >> 2, seg = t & 3;
    u16x8 o0, o1;
    #pragma unroll
    for (int j = 0; j < 8; ++j) {
        o0[j] = ts[px * 72 + seg * 16 + j];
        o1[j] = ts[px * 72 + seg * 16 + 8 + j];
    }
    const size_t base = ((size_t)(b * P_ + px0 + px)) * C + c0 + seg * 16;
    *(u16x8*)&out[base]     = o0;
    *(u16x8*)&out[base + 8] = o1;
}

// ---------------------------------------------------------------------------
// conv3x3 as 9 shifted-tap MFMA GEMMs. grid (64 y, 8 b, 3 oc-thirds),
// 128 thr (2 waves): wave w = px-half (32 px), both nj (32 oc of this third).
// LDS: x-tile only, 3 rows x 66 slots x 64 ic (guard cols). Boundary rows
// zeroed once -> branch-free fully-unrolled 9-tap loop. B from global (L2).
// ---------------------------------------------------------------------------
__global__ __launch_bounds__(128, 3) void conv3x3_mfma(
    const u16* __restrict__ xbf, const u16* __restrict__ wconv,
    const float* __restrict__ off_b, const float* __restrict__ attn_b,
    u16* __restrict__ convout) {
    const int y = blockIdx.x, b = blockIdx.y, oh = blockIdx.z;
    const int tid = threadIdx.x, w = tid >> 6, lane = tid & 63, g = lane >> 4, i = lane & 15;
    __shared__ u16 xs[3 * 66 * 64];    // [row r][slot 0..65][64 ic], slot = x+1

    f32x4 acc[2][2];
    #pragma unroll
    for (int mi = 0; mi < 2; ++mi)
        #pragma unroll
        for (int nj = 0; nj < 2; ++nj) acc[mi][nj] = (f32x4){0.f, 0.f, 0.f, 0.f};

    // zero guard slots (slot 0 and 65 of each row), once
    if (tid < 48) {
        const int r = tid >> 4, q = tid & 15;
        const int slot = (q < 8) ? 0 : 65, c = q & 7;
        *(u16x8*)&xs[(r * 66 + slot) * 64 + c * 8] = (u16x8){0, 0, 0, 0, 0, 0, 0, 0};
    }
    // zero out-of-range rows once (never staged), so tap loop is branch-free
    if (y == 0) {
        #pragma unroll
        for (int t = 0; t < 4; ++t)
            *(u16x8*)&xs[66 * 0 * 64 + 64 + tid * 32 + t * 8] = (u16x8){0,0,0,0,0,0,0,0};
    }
    if (y == 63) {
        #pragma unroll
        for (int t = 0; t < 4; ++t)
            *(u16x8*)&xs[66 * 2 * 64 + 64 + tid * 32 + t * 8] = (u16x8){0,0,0,0,0,0,0,0};
    }

    // per-lane A-read offsets: [mi][dx][ks]
    int aoff[2][3][2];
    #pragma unroll
    for (int mi = 0; mi < 2; ++mi)
        #pragma unroll
        for (int dx = 0; dx < 3; ++dx)
            #pragma unroll
            for (int ks = 0; ks < 2; ++ks) {
                const int x = w * 32 + mi * 16 + i;
                const int slot = x + dx;            // (x+dx-1)+1
                aoff[mi][dx][ks] = slot * 64 + (((ks * 4 + g) ^ (slot & 7)) << 3);
            }

    for (int cc = 0; cc < 4; ++cc) {
        const int ic0 = cc * 64;
        #pragma unroll
        for (int r = 0; r < 3; ++r) {
            const int yy = y + r - 1;
            if ((unsigned)yy < 64u) {
                #pragma unroll
                for (int t = 0; t < 4; ++t) {
                    const int ii = w * 4 + t;                    // 0..7
                    const int px = ii * 8 + (lane >> 3), c = lane & 7;
                    const u16* src = xbf + (((size_t)(b * P_ + yy * 64 + px)) << 8) + ic0
                                     + ((c ^ ((px + 1) & 7)) << 3);
                    gload16(src, &xs[(r * 66 + ii * 8 + 1) * 64]);
                }
            }
        }
        __syncthreads();
        #pragma unroll
        for (int tap = 0; tap < 9; ++tap) {
            const int dy = tap / 3, dxv = tap % 3;
            const u16* wt = wconv + (((size_t)(tap * 96 + oh * 32 + i)) << 8) + ic0 + (g << 3);
            const u16x8 b00 = *(const u16x8*)&wt[0];
            const u16x8 b01 = *(const u16x8*)&wt[16 << 8];
            const u16x8 b10 = *(const u16x8*)&wt[32];
            const u16x8 b11 = *(const u16x8*)&wt[(16 << 8) + 32];
            const u16x8 a0k0 = *(const u16x8*)&xs[dy * 4224 + aoff[0][dxv][0]];
            const u16x8 a1k0 = *(const u16x8*)&xs[dy * 4224 + aoff[1][dxv][0]];
            const u16x8 a0k1 = *(const u16x8*)&xs[dy * 4224 + aoff[0][dxv][1]];
            const u16x8 a1k1 = *(const u16x8*)&xs[dy * 4224 + aoff[1][dxv][1]];
            acc[0][0] = mfma16(a0k0, b00, acc[0][0]);
            acc[1][0] = mfma16(a1k0, b00, acc[1][0]);
            acc[0][1] = mfma16(a0k0, b01, acc[0][1]);
            acc[1][1] = mfma16(a1k0, b01, acc[1][1]);
            acc[0][0] = mfma16(a0k1, b10, acc[0][0]);
            acc[1][0] = mfma16(a1k1, b10, acc[1][0]);
            acc[0][1] = mfma16(a0k1, b11, acc[0][1]);
            acc[1][1] = mfma16(a1k1, b11, acc[1][1]);
        }
        __syncthreads();
    }
    #pragma unroll
    for (int mi = 0; mi < 2; ++mi) {
        const int x0 = w * 32 + mi * 16 + g * 4;
        #pragma unroll
        for (int nj = 0; nj < 2; ++nj) {
            const int oc = oh * 32 + nj * 16 + i;
            const float bv = (oc < 64) ? off_b[oc] : attn_b[oc - 64];
            #pragma unroll
            for (int r = 0; r < 4; ++r)
                convout[((size_t)(b * P_ + y * 64 + x0 + r)) * 96 + oc] =
                    f2bf(acc[mi][nj][r] + bv);
        }
    }
}

// ---------------------------------------------------------------------------
// 128x128-tile NHWC bf16 MFMA GEMM, K-chunk 128, both operands via
// global_load_lds. grid (32, OC/128, 8), 256 thr (4 waves, 64x64 quadrants).
// mode 0: +bias -> bf16 NHWC; 1: +bias,relu -> bf16 NHWC;
// 2: +bias +resid(f32 NCHW) -> f32 NCHW; 3: mode2 AND bf16 NHWC copy.
// ---------------------------------------------------------------------------
__global__ __launch_bounds__(256, 2) void gemm128(
    const u16* __restrict__ X, const u16* __restrict__ W,
    const float* __restrict__ bias, const float* __restrict__ resid,
    void* __restrict__ outp, u16* __restrict__ out_nhwc,
    const int KTOT, const int OC, const int mode) {
    const int px0 = blockIdx.x * 128, oc0 = blockIdx.y * 128, b = blockIdx.z;
    const int tid = threadIdx.x, w = tid >> 6, lane = tid & 63, g = lane >> 4, i = lane & 15;
    const int wm = w & 1, wn = w >> 1;
    __shared__ u16 lds[32768];           // 64 KB: X tile [128][128] + W tile [128][128]
    u16* xs = lds;
    u16* wsL = lds + 16384;

    f32x4 acc[4][4];
    #pragma unroll
    for (int mi = 0; mi < 4; ++mi)
        #pragma unroll
        for (int nj = 0; nj < 4; ++nj) acc[mi][nj] = (f32x4){0.f, 0.f, 0.f, 0.f};

    const int srow = (lane >> 4), sc = lane & 15;   // staging: 4 rows x 16 chunks
    for (int kc = 0; kc < KTOT; kc += 128) {
        #pragma unroll
        for (int t = 0; t < 8; ++t) {
            const int j = w * 8 + t;                // 0..31
            const int row = j * 4 + srow;
            const int cs = sc ^ (row & 7);
            gload16(X + (size_t)(b * P_ + px0 + row) * KTOT + kc + (cs << 3), &xs[j * 512]);
        }
        #pragma unroll
        for (int t = 0; t < 8; ++t) {
            const int j = w * 8 + t;
            const int row = j * 4 + srow;
            const int cs = sc ^ (row & 7);
            gload16(W + (size_t)(oc0 + row) * KTOT + kc + (cs << 3), &wsL[j * 512]);
        }
        __syncthreads();
        #pragma unroll
        for (int ks = 0; ks < 4; ++ks) {
            u16x8 a[4], bb[4];
            #pragma unroll
            for (int mi = 0; mi < 4; ++mi) {
                const int px = wm * 64 + mi * 16 + i;
                a[mi] = *(const u16x8*)&xs[px * 128 + (((ks * 4 + g) ^ (px & 7)) << 3)];
            }
            #pragma unroll
            for (int nj = 0; nj < 4; ++nj) {
                const int oc = wn * 64 + nj * 16 + i;
                bb[nj] = *(const u16x8*)&wsL[oc * 128 + (((ks * 4 + g) ^ (oc & 7)) << 3)];
            }
            #pragma unroll
            for (int mi = 0; mi < 4; ++mi)
                #pragma unroll
                for (int nj = 0; nj < 4; ++nj)
                    acc[mi][nj] = mfma16(a[mi], bb[nj], acc[mi][nj]);
        }
        __syncthreads();
    }

    if (mode < 2) {
        u16* out = (u16*)outp;
        #pragma unroll
        for (int mi = 0; mi < 4; ++mi) {
            #pragma unroll
            for (int nj = 0; nj < 4; ++nj) {
                const int ocg = oc0 + wn * 64 + nj * 16 + i;
                const float bv = bias[ocg];
                #pragma unroll
                for (int r = 0; r < 4; ++r) {
                    const int px = px0 + wm * 64 + mi * 16 + g * 4 + r;
                    float v = acc[mi][nj][r] + bv;
                    if (mode == 1) v = fmaxf(v, 0.f);
                    out[((size_t)(b * P_ + px)) * OC + ocg] = f2bf(v);
                }
            }
        }
    } else {
        float* lf = (float*)lds;          // [128 oc][66 px] f32 = 33792 B
        float* out = (float*)outp;
        #pragma unroll
        for (int h = 0; h < 2; ++h) {
            if (wm == h) {
                #pragma unroll
                for (int mi = 0; mi < 4; ++mi)
                    #pragma unroll
                    for (int nj = 0; nj < 4; ++nj) {
                        const int ocl = wn * 64 + nj * 16 + i;
                        const float bv = bias[oc0 + ocl];
                        #pragma unroll
                        for (int r = 0; r < 4; ++r)
                            lf[ocl * 66 + mi * 16 + g * 4 + r] = acc[mi][nj][r] + bv;
                    }
            }
            __syncthreads();
            {
                const int ocl = tid >> 1, sh = (tid & 1) * 32;
                const size_t base = ((size_t)b * OC + oc0 + ocl) * P_ + px0 + h * 64 + sh;
                #pragma unroll
                for (int q = 0; q < 8; ++q) {
                    const float4 r4 = *(const float4*)&resid[base + q * 4];
                    float4 o;
                    o.x = lf[ocl * 66 + sh + q * 4 + 0] + r4.x;
                    o.y = lf[ocl * 66 + sh + q * 4 + 1] + r4.y;
                    o.z = lf[ocl * 66 + sh + q * 4 + 2] + r4.z;
                    o.w = lf[ocl * 66 + sh + q * 4 + 3] + r4.w;
                    *(float4*)&out[base + q * 4] = o;
                    if (mode == 3) {   // write the resid-added value back for NHWC copy
                        lf[ocl * 66 + sh + q * 4 + 0] = o.x;
                        lf[ocl * 66 + sh + q * 4 + 1] = o.y;
                        lf[ocl * 66 + sh + q * 4 + 2] = o.z;
                        lf[ocl * 66 + sh + q * 4 + 3] = o.w;
                    }
                }
            }
            if (mode == 3) {
                __syncthreads();   // lf write-back visible to all threads
                const int pxl = tid >> 2, seg = tid & 3;
                const size_t b2 = ((size_t)(b * P_ + px0 + h * 64 + pxl)) * OC + oc0 + seg * 32;
                #pragma unroll
                for (int t = 0; t < 4; ++t) {
                    u16x8 o8;
                    #pragma unroll
                    for (int j = 0; j < 8; ++j)
                        o8[j] = f2bf(lf[(seg * 32 + t * 8 + j) * 66 + pxl]);
                    *(u16x8*)&out_nhwc[b2 + t * 8] = o8;
                }
            }
            __syncthreads();
        }
    }
}

// ---------------------------------------------------------------------------
// softmax over K + bilinear grid-sample + weighted sum. NHWC bf16 in/out.
// ---------------------------------------------------------------------------
__global__ __launch_bounds__(256) void sample_attend_bf(
    const u16* __restrict__ value, const u16* __restrict__ conv,
    u16* __restrict__ out1) {
    const int y = blockIdx.x, m = blockIdx.y, b = blockIdx.z;
    const int tid = threadIdx.x, x = tid >> 2, gq = tid & 3;
    const size_t prow = (size_t)(b * P_ + y * 64 + x);

    const u16x8 ov = *(const u16x8*)&conv[prow * 96 + m * 8];
    const u16x4 av = *(const u16x4*)&conv[prow * 96 + 64 + m * 4];

    float a[4];
    #pragma unroll
    for (int k = 0; k < 4; ++k) a[k] = bf2f(av[k]);
    const float mx = fmaxf(fmaxf(a[0], a[1]), fmaxf(a[2], a[3]));
    float s = 0.f;
    #pragma unroll
    for (int k = 0; k < 4; ++k) { a[k] = __expf(a[k] - mx); s += a[k]; }
    const float inv = 1.f / s;

    float acc[8];
    #pragma unroll
    for (int j = 0; j < 8; ++j) acc[j] = 0.f;

    const u16* vb = value + ((size_t)b * P_) * 256 + m * 32 + gq * 8;

    #pragma unroll
    for (int k = 0; k < 4; ++k) {
        const float offx = bf2f(ov[2 * k]), offy = bf2f(ov[2 * k + 1]);
        const float px = (float)(63 - x) + offx;
        const float py = (float)y + offy;
        const float x0f = floorf(px), y0f = floorf(py);
        const int xi0 = (int)x0f, yi0 = (int)y0f;
        const float wx = px - x0f, wy = py - y0f;
        const int xi1 = xi0 + 1, yi1 = yi0 + 1;
        const bool vx0 = (xi0 >= 0) & (xi0 <= 63), vx1 = (xi1 >= 0) & (xi1 <= 63);
        const bool vy0 = (yi0 >= 0) & (yi0 <= 63), vy1 = (yi1 >= 0) & (yi1 <= 63);
        const int cx0 = min(max(xi0, 0), 63), cx1 = min(max(xi1, 0), 63);
        const int cy0 = min(max(yi0, 0), 63), cy1 = min(max(yi1, 0), 63);
        const float ak = a[k] * inv;
        const float c00 = ak * (1.f - wx) * (1.f - wy) * ((vx0 & vy0) ? 1.f : 0.f);
        const float c01 = ak * wx * (1.f - wy) * ((vx1 & vy0) ? 1.f : 0.f);
        const float c10 = ak * (1.f - wx) * wy * ((vx0 & vy1) ? 1.f : 0.f);
        const float c11 = ak * wx * wy * ((vx1 & vy1) ? 1.f : 0.f);
        const u16x8 v00 = *(const u16x8*)&vb[(size_t)(cy0 * 64 + cx0) * 256];
        const u16x8 v01 = *(const u16x8*)&vb[(size_t)(cy0 * 64 + cx1) * 256];
        const u16x8 v10 = *(const u16x8*)&vb[(size_t)(cy1 * 64 + cx0) * 256];
        const u16x8 v11 = *(const u16x8*)&vb[(size_t)(cy1 * 64 + cx1) * 256];
        #pragma unroll
        for (int j = 0; j < 8; ++j)
            acc[j] += c00 * bf2f(v00[j]) + c01 * bf2f(v01[j])
                    + c10 * bf2f(v10[j]) + c11 * bf2f(v11[j]);
    }
    u16x8 o;
    #pragma unroll
    for (int j = 0; j < 8; ++j) o[j] = f2bf(acc[j]);
    *(u16x8*)&out1[prow * 256 + m * 32 + gq * 8] = o;
}

// ---------------------------------------------------------------------------
extern "C" void kernel_launch(void* const* d_in, const int* in_sizes, int n_in,
                              void* d_out, int out_size, void* d_ws, size_t ws_size,
                              hipStream_t stream) {
    const float* f_recalib = (const float*)d_in[0];
    const float* f_orig    = (const float*)d_in[1];
    const float* offset_w  = (const float*)d_in[2];
    const float* offset_b  = (const float*)d_in[3];
    const float* attn_w    = (const float*)d_in[4];
    const float* attn_b    = (const float*)d_in[5];
    const float* value_w   = (const float*)d_in[6];
    const float* value_b   = (const float*)d_in[7];
    const float* proj_w    = (const float*)d_in[8];
    const float* proj_b    = (const float*)d_in[9];
    const float* mlp_w1    = (const float*)d_in[10];
    const float* mlp_b1    = (const float*)d_in[11];
    const float* mlp_w2    = (const float*)d_in[12];
    const float* mlp_b2    = (const float*)d_in[13];
    float* out = (float*)d_out;

    u16* wsb      = (u16*)d_ws;
    u16* x_bf     = wsb;                  // 8,388,608 u16 (16 MB)
    u16* convout  = wsb + 8388608;        // 3,145,728 (6 MB)
    u16* value_bf = wsb + 11534336;       // 8,388,608 (16 MB)
    u16* out1_bf  = wsb + 19922944;       // 8,388,608 (16 MB)
    u16* wbf      = wsb + 28311552;       // 614,400 (1.2 MB) -> 55.2 MB total
    u16* out2_bf  = x_bf;                 // alias: x_bf dead after value GEMM+conv
    u16* h_bf     = wsb + 8388608;        // alias convout..out1 (all dead by mlp1), 32 MB

    u16* wconv = wbf;
    u16* wval  = wbf + 221184;
    u16* wproj = wbf + 286720;
    u16* wmlp1 = wbf + 352256;
    u16* wmlp2 = wbf + 483328;

    prep_weights<<<2400, 256, 0, stream>>>(offset_w, attn_w, value_w, proj_w,
                                           mlp_w1, mlp_w2, wbf);
    to_nhwc_bf16<<<dim3(64, 4, 8), 256, 0, stream>>>(f_recalib, x_bf, 256);
    conv3x3_mfma<<<dim3(64, 8, 3), 128, 0, stream>>>(x_bf, wconv, offset_b, attn_b, convout);
    gemm128<<<dim3(32, 2, 8), 256, 0, stream>>>(x_bf, wval, value_b, nullptr,
                                                value_bf, nullptr, 256, 256, 0);
    sample_attend_bf<<<dim3(64, 8, 8), 256, 0, stream>>>(value_bf, convout, out1_bf);
    // proj + f_orig -> d_out (f32 NCHW) AND out2_bf (bf16 NHWC), fused
    gemm128<<<dim3(32, 2, 8), 256, 0, stream>>>(out1_bf, wproj, proj_b, f_orig,
                                                out, out2_bf, 256, 256, 3);
    gemm128<<<dim3(32, 4, 8), 256, 0, stream>>>(out2_bf, wmlp1, mlp_b1, nullptr,
                                                h_bf, nullptr, 256, 512, 1);
    gemm128<<<dim3(32, 2, 8), 256, 0, stream>>>(h_bf, wmlp2, mlp_b2, out,
                                                out, nullptr, 512, 256, 2);
}

// Round 7
// 167.080 us; speedup vs baseline: 5.2490x; 1.1652x over previous
//
#include <hip/hip_runtime.h>
#include <cstddef>

#define P_ 4096
#define PW_ 66   // padded width/height

using u16 = unsigned short;
typedef float  f32x4  __attribute__((ext_vector_type(4)));
typedef u16    u16x8  __attribute__((ext_vector_type(8)));
typedef u16    u16x4  __attribute__((ext_vector_type(4)));
typedef __bf16 bf16x8 __attribute__((ext_vector_type(8)));

#define DEVINL __device__ __forceinline__

DEVINL u16 f2bf(float f) {
    union { float f; unsigned u; } v; v.f = f;
    unsigned r = v.u + 0x7fffu + ((v.u >> 16) & 1u);
    return (u16)(r >> 16);
}
DEVINL float bf2f(u16 h) {
    union { unsigned u; float f; } v; v.u = ((unsigned)h) << 16;
    return v.f;
}

DEVINL f32x4 mfma16(u16x8 a, u16x8 b, f32x4 c) {
    return __builtin_amdgcn_mfma_f32_16x16x32_bf16(
        __builtin_bit_cast(bf16x8, a), __builtin_bit_cast(bf16x8, b), c, 0, 0, 0);
}

DEVINL void gload16(const u16* src, const u16* lds_dst) {
    __builtin_amdgcn_global_load_lds(
        (const __attribute__((address_space(1))) void*)src,
        (__attribute__((address_space(3))) void*)lds_dst, 16, 0, 0);
}

// ---------------------------------------------------------------------------
// prep_weights: all weights -> bf16. conv weights reordered to [tap][96][256].
// ---------------------------------------------------------------------------
__global__ void prep_weights(const float* __restrict__ off_w, const float* __restrict__ attn_w,
                             const float* __restrict__ val_w, const float* __restrict__ proj_w,
                             const float* __restrict__ w1, const float* __restrict__ w2,
                             u16* __restrict__ wbf) {
    int idx = blockIdx.x * 256 + threadIdx.x;
    if (idx >= 614400) return;
    float v;
    if (idx < 221184) {
        int tap = idx / 24576, rem = idx - tap * 24576, oc = rem >> 8, ic = rem & 255;
        v = (oc < 64) ? off_w[(size_t)(oc * 256 + ic) * 9 + tap]
                      : attn_w[(size_t)((oc - 64) * 256 + ic) * 9 + tap];
    } else if (idx < 286720) v = val_w[idx - 221184];
    else if (idx < 352256)   v = proj_w[idx - 286720];
    else if (idx < 483328)   v = w1[idx - 352256];
    else                     v = w2[idx - 483328];
    wbf[idx] = f2bf(v);
}

// ---------------------------------------------------------------------------
// zero the 260 pad pixels per batch of the padded NHWC image. grid (8).
// ---------------------------------------------------------------------------
__global__ __launch_bounds__(256) void zero_pad(u16* __restrict__ xp) {
    const int b = blockIdx.x, t = threadIdx.x;
    const u16x8 z = (u16x8){0, 0, 0, 0, 0, 0, 0, 0};
    for (int q = t; q < 8320; q += 256) {
        const int p = q >> 5, chunk = q & 31;
        int row, col;
        if (p < 66)       { row = 0;  col = p; }
        else if (p < 132) { row = 65; col = p - 66; }
        else { const int q2 = p - 132; row = 1 + (q2 >> 1); col = (q2 & 1) * 65; }
        *(u16x8*)&xp[((size_t)(b * PW_ + row) * PW_ + col) * 256 + chunk * 8] = z;
    }
}

// ---------------------------------------------------------------------------
// NCHW fp32 -> padded NHWC bf16. grid (64 y, 4 cgroup, 8 b), 256 thr.
// writes interior pixels of xp[b][y+1][x+1][c].
// ---------------------------------------------------------------------------
__global__ __launch_bounds__(256) void to_nhwc_pad(const float* __restrict__ in,
                                                   u16* __restrict__ xp) {
    const int y = blockIdx.x, c0 = blockIdx.y * 64, b = blockIdx.z;
    __shared__ u16 ts[64 * 72];
    const int t = threadIdx.x, cl = t >> 4, xq = t & 15;
    #pragma unroll
    for (int r = 0; r < 4; ++r) {
        const int c = r * 16 + cl;
        const float4 v = *(const float4*)&in[((size_t)(b * 256 + c0 + c)) * P_ + y * 64 + xq * 4];
        ts[(xq * 4 + 0) * 72 + c] = f2bf(v.x);
        ts[(xq * 4 + 1) * 72 + c] = f2bf(v.y);
        ts[(xq * 4 + 2) * 72 + c] = f2bf(v.z);
        ts[(xq * 4 + 3) * 72 + c] = f2bf(v.w);
    }
    __syncthreads();
    const int px = t >> 2, seg = t & 3;
    u16x8 o0, o1;
    #pragma unroll
    for (int j = 0; j < 8; ++j) {
        o0[j] = ts[px * 72 + seg * 16 + j];
        o1[j] = ts[px * 72 + seg * 16 + 8 + j];
    }
    const size_t base = ((size_t)(b * PW_ + y + 1) * PW_ + 1 + px) * 256 + c0 + seg * 16;
    *(u16x8*)&xp[base]     = o0;
    *(u16x8*)&xp[base + 8] = o1;
}

// ---------------------------------------------------------------------------
// conv3x3 as 9 shifted full-GEMMs over padded input. grid (64 y, 8 b),
// 256 thr (4 waves: wm=w&1 px-half 32, wn=w>>1 oc-half 48). LDS: A 64x128
// (16KB) + W 96x128 (24KB) = 40KB -> 4 blocks/CU. 18 stage/compute rounds.
// ---------------------------------------------------------------------------
__global__ __launch_bounds__(256, 4) void conv3x3_mfma(
    const u16* __restrict__ xp, const u16* __restrict__ wconv,
    const float* __restrict__ off_b, const float* __restrict__ attn_b,
    u16* __restrict__ convout) {
    const int y = blockIdx.x, b = blockIdx.y;
    const int tid = threadIdx.x, w = tid >> 6, lane = tid & 63, g = lane >> 4, i = lane & 15;
    const int wm = w & 1, wn = w >> 1;
    const int srow = lane >> 4, sc = lane & 15;
    __shared__ u16 xs[64 * 128];     // [x 64][128 ic]
    __shared__ u16 wsL[96 * 128];    // [oc 96][128 ic]

    f32x4 acc[2][3];
    #pragma unroll
    for (int mi = 0; mi < 2; ++mi)
        #pragma unroll
        for (int nj = 0; nj < 3; ++nj) acc[mi][nj] = (f32x4){0.f, 0.f, 0.f, 0.f};

    for (int tap = 0; tap < 9; ++tap) {
        const int dy = tap / 3, dx = tap % 3;
        const u16* xrow = xp + ((size_t)(b * PW_ + y + dy) * PW_ + dx) * 256;
        const u16* wt = wconv + (size_t)(tap * 96) * 256;
        for (int cc = 0; cc < 2; ++cc) {
            const int kc = cc * 128;
            // stage A: 16 loads (4/wave)
            #pragma unroll
            for (int t = 0; t < 4; ++t) {
                const int j = w * 4 + t;
                const int row = j * 4 + srow;              // x coord 0..63
                const int cs = sc ^ (row & 7);
                gload16(xrow + (size_t)row * 256 + kc + (cs << 3), &xs[j * 512]);
            }
            // stage W: 24 loads (6/wave)
            #pragma unroll
            for (int t = 0; t < 6; ++t) {
                const int j = w * 6 + t;
                const int row = j * 4 + srow;              // oc 0..95
                const int cs = sc ^ (row & 7);
                gload16(wt + (size_t)row * 256 + kc + (cs << 3), &wsL[j * 512]);
            }
            __syncthreads();
            #pragma unroll
            for (int ks = 0; ks < 4; ++ks) {
                u16x8 a[2], bb[3];
                #pragma unroll
                for (int mi = 0; mi < 2; ++mi) {
                    const int pr = wm * 32 + mi * 16 + i;
                    a[mi] = *(const u16x8*)&xs[pr * 128 + (((ks * 4 + g) ^ (pr & 7)) << 3)];
                }
                #pragma unroll
                for (int nj = 0; nj < 3; ++nj) {
                    const int ocr = wn * 48 + nj * 16 + i;
                    bb[nj] = *(const u16x8*)&wsL[ocr * 128 + (((ks * 4 + g) ^ (ocr & 7)) << 3)];
                }
                #pragma unroll
                for (int mi = 0; mi < 2; ++mi)
                    #pragma unroll
                    for (int nj = 0; nj < 3; ++nj)
                        acc[mi][nj] = mfma16(a[mi], bb[nj], acc[mi][nj]);
            }
            __syncthreads();
        }
    }
    #pragma unroll
    for (int mi = 0; mi < 2; ++mi) {
        const int x0 = wm * 32 + mi * 16 + g * 4;
        #pragma unroll
        for (int nj = 0; nj < 3; ++nj) {
            const int oc = wn * 48 + nj * 16 + i;
            const float bv = (oc < 64) ? off_b[oc] : attn_b[oc - 64];
            #pragma unroll
            for (int r = 0; r < 4; ++r)
                convout[((size_t)(b * P_ + y * 64 + x0 + r)) * 96 + oc] =
                    f2bf(acc[mi][nj][r] + bv);
        }
    }
}

// ---------------------------------------------------------------------------
// 128x128-tile NHWC bf16 MFMA GEMM, K-chunk 128, both operands via
// global_load_lds. grid (32, OC/128, 8), 256 thr (4 waves, 64x64 quadrants).
// padded=1: X is the 66x66 padded image (KTOT must be 256).
// mode 0: +bias -> bf16 NHWC; 1: +bias,relu -> bf16 NHWC;
// 2: +bias +resid(f32 NCHW) -> f32 NCHW; 3: mode2 AND bf16 NHWC copy.
// ---------------------------------------------------------------------------
__global__ __launch_bounds__(256, 2) void gemm128(
    const u16* __restrict__ X, const u16* __restrict__ W,
    const float* __restrict__ bias, const float* __restrict__ resid,
    void* __restrict__ outp, u16* __restrict__ out_nhwc,
    const int KTOT, const int OC, const int mode, const int padded) {
    const int px0 = blockIdx.x * 128, oc0 = blockIdx.y * 128, b = blockIdx.z;
    const int tid = threadIdx.x, w = tid >> 6, lane = tid & 63, g = lane >> 4, i = lane & 15;
    const int wm = w & 1, wn = w >> 1;
    __shared__ u16 lds[32768];           // 64 KB: X tile [128][128] + W tile [128][128]
    u16* xs = lds;
    u16* wsL = lds + 16384;

    f32x4 acc[4][4];
    #pragma unroll
    for (int mi = 0; mi < 4; ++mi)
        #pragma unroll
        for (int nj = 0; nj < 4; ++nj) acc[mi][nj] = (f32x4){0.f, 0.f, 0.f, 0.f};

    const int srow = (lane >> 4), sc = lane & 15;   // staging: 4 rows x 16 chunks
    for (int kc = 0; kc < KTOT; kc += 128) {
        #pragma unroll
        for (int t = 0; t < 8; ++t) {
            const int j = w * 8 + t;                // 0..31
            const int row = j * 4 + srow;
            const int cs = sc ^ (row & 7);
            const u16* srcA;
            if (padded) {
                const int pxg = px0 + row;
                srcA = X + ((size_t)(b * PW_ + (pxg >> 6) + 1) * PW_ + (pxg & 63) + 1) * 256
                         + kc + (cs << 3);
            } else {
                srcA = X + (size_t)(b * P_ + px0 + row) * KTOT + kc + (cs << 3);
            }
            gload16(srcA, &xs[j * 512]);
        }
        #pragma unroll
        for (int t = 0; t < 8; ++t) {
            const int j = w * 8 + t;
            const int row = j * 4 + srow;
            const int cs = sc ^ (row & 7);
            gload16(W + (size_t)(oc0 + row) * KTOT + kc + (cs << 3), &wsL[j * 512]);
        }
        __syncthreads();
        #pragma unroll
        for (int ks = 0; ks < 4; ++ks) {
            u16x8 a[4], bb[4];
            #pragma unroll
            for (int mi = 0; mi < 4; ++mi) {
                const int px = wm * 64 + mi * 16 + i;
                a[mi] = *(const u16x8*)&xs[px * 128 + (((ks * 4 + g) ^ (px & 7)) << 3)];
            }
            #pragma unroll
            for (int nj = 0; nj < 4; ++nj) {
                const int oc = wn * 64 + nj * 16 + i;
                bb[nj] = *(const u16x8*)&wsL[oc * 128 + (((ks * 4 + g) ^ (oc & 7)) << 3)];
            }
            #pragma unroll
            for (int mi = 0; mi < 4; ++mi)
                #pragma unroll
                for (int nj = 0; nj < 4; ++nj)
                    acc[mi][nj] = mfma16(a[mi], bb[nj], acc[mi][nj]);
        }
        __syncthreads();
    }

    if (mode < 2) {
        u16* out = (u16*)outp;
        #pragma unroll
        for (int mi = 0; mi < 4; ++mi) {
            #pragma unroll
            for (int nj = 0; nj < 4; ++nj) {
                const int ocg = oc0 + wn * 64 + nj * 16 + i;
                const float bv = bias[ocg];
                #pragma unroll
                for (int r = 0; r < 4; ++r) {
                    const int px = px0 + wm * 64 + mi * 16 + g * 4 + r;
                    float v = acc[mi][nj][r] + bv;
                    if (mode == 1) v = fmaxf(v, 0.f);
                    out[((size_t)(b * P_ + px)) * OC + ocg] = f2bf(v);
                }
            }
        }
    } else {
        float* lf = (float*)lds;          // [128 oc][66 px] f32 = 33792 B
        float* out = (float*)outp;
        #pragma unroll
        for (int h = 0; h < 2; ++h) {
            if (wm == h) {
                #pragma unroll
                for (int mi = 0; mi < 4; ++mi)
                    #pragma unroll
                    for (int nj = 0; nj < 4; ++nj) {
                        const int ocl = wn * 64 + nj * 16 + i;
                        const float bv = bias[oc0 + ocl];
                        #pragma unroll
                        for (int r = 0; r < 4; ++r)
                            lf[ocl * 66 + mi * 16 + g * 4 + r] = acc[mi][nj][r] + bv;
                    }
            }
            __syncthreads();
            {
                const int ocl = tid >> 1, sh = (tid & 1) * 32;
                const size_t base = ((size_t)b * OC + oc0 + ocl) * P_ + px0 + h * 64 + sh;
                #pragma unroll
                for (int q = 0; q < 8; ++q) {
                    const float4 r4 = *(const float4*)&resid[base + q * 4];
                    float4 o;
                    o.x = lf[ocl * 66 + sh + q * 4 + 0] + r4.x;
                    o.y = lf[ocl * 66 + sh + q * 4 + 1] + r4.y;
                    o.z = lf[ocl * 66 + sh + q * 4 + 2] + r4.z;
                    o.w = lf[ocl * 66 + sh + q * 4 + 3] + r4.w;
                    *(float4*)&out[base + q * 4] = o;
                    if (mode == 3) {   // write the resid-added value back for NHWC copy
                        lf[ocl * 66 + sh + q * 4 + 0] = o.x;
                        lf[ocl * 66 + sh + q * 4 + 1] = o.y;
                        lf[ocl * 66 + sh + q * 4 + 2] = o.z;
                        lf[ocl * 66 + sh + q * 4 + 3] = o.w;
                    }
                }
            }
            if (mode == 3) {
                __syncthreads();   // lf write-back visible to all threads
                const int pxl = tid >> 2, seg = tid & 3;
                const size_t b2 = ((size_t)(b * P_ + px0 + h * 64 + pxl)) * OC + oc0 + seg * 32;
                #pragma unroll
                for (int t = 0; t < 4; ++t) {
                    u16x8 o8;
                    #pragma unroll
                    for (int j = 0; j < 8; ++j)
                        o8[j] = f2bf(lf[(seg * 32 + t * 8 + j) * 66 + pxl]);
                    *(u16x8*)&out_nhwc[b2 + t * 8] = o8;
                }
            }
            __syncthreads();
        }
    }
}

// ---------------------------------------------------------------------------
// softmax over K + bilinear grid-sample + weighted sum. NHWC bf16 in/out.
// ---------------------------------------------------------------------------
__global__ __launch_bounds__(256) void sample_attend_bf(
    const u16* __restrict__ value, const u16* __restrict__ conv,
    u16* __restrict__ out1) {
    const int y = blockIdx.x, m = blockIdx.y, b = blockIdx.z;
    const int tid = threadIdx.x, x = tid >> 2, gq = tid & 3;
    const size_t prow = (size_t)(b * P_ + y * 64 + x);

    const u16x8 ov = *(const u16x8*)&conv[prow * 96 + m * 8];
    const u16x4 av = *(const u16x4*)&conv[prow * 96 + 64 + m * 4];

    float a[4];
    #pragma unroll
    for (int k = 0; k < 4; ++k) a[k] = bf2f(av[k]);
    const float mx = fmaxf(fmaxf(a[0], a[1]), fmaxf(a[2], a[3]));
    float s = 0.f;
    #pragma unroll
    for (int k = 0; k < 4; ++k) { a[k] = __expf(a[k] - mx); s += a[k]; }
    const float inv = 1.f / s;

    float acc[8];
    #pragma unroll
    for (int j = 0; j < 8; ++j) acc[j] = 0.f;

    const u16* vb = value + ((size_t)b * P_) * 256 + m * 32 + gq * 8;

    #pragma unroll
    for (int k = 0; k < 4; ++k) {
        const float offx = bf2f(ov[2 * k]), offy = bf2f(ov[2 * k + 1]);
        const float px = (float)(63 - x) + offx;
        const float py = (float)y + offy;
        const float x0f = floorf(px), y0f = floorf(py);
        const int xi0 = (int)x0f, yi0 = (int)y0f;
        const float wx = px - x0f, wy = py - y0f;
        const int xi1 = xi0 + 1, yi1 = yi0 + 1;
        const bool vx0 = (xi0 >= 0) & (xi0 <= 63), vx1 = (xi1 >= 0) & (xi1 <= 63);
        const bool vy0 = (yi0 >= 0) & (yi0 <= 63), vy1 = (yi1 >= 0) & (yi1 <= 63);
        const int cx0 = min(max(xi0, 0), 63), cx1 = min(max(xi1, 0), 63);
        const int cy0 = min(max(yi0, 0), 63), cy1 = min(max(yi1, 0), 63);
        const float ak = a[k] * inv;
        const float c00 = ak * (1.f - wx) * (1.f - wy) * ((vx0 & vy0) ? 1.f : 0.f);
        const float c01 = ak * wx * (1.f - wy) * ((vx1 & vy0) ? 1.f : 0.f);
        const float c10 = ak * (1.f - wx) * wy * ((vx0 & vy1) ? 1.f : 0.f);
        const float c11 = ak * wx * wy * ((vx1 & vy1) ? 1.f : 0.f);
        const u16x8 v00 = *(const u16x8*)&vb[(size_t)(cy0 * 64 + cx0) * 256];
        const u16x8 v01 = *(const u16x8*)&vb[(size_t)(cy0 * 64 + cx1) * 256];
        const u16x8 v10 = *(const u16x8*)&vb[(size_t)(cy1 * 64 + cx0) * 256];
        const u16x8 v11 = *(const u16x8*)&vb[(size_t)(cy1 * 64 + cx1) * 256];
        #pragma unroll
        for (int j = 0; j < 8; ++j)
            acc[j] += c00 * bf2f(v00[j]) + c01 * bf2f(v01[j])
                    + c10 * bf2f(v10[j]) + c11 * bf2f(v11[j]);
    }
    u16x8 o;
    #pragma unroll
    for (int j = 0; j < 8; ++j) o[j] = f2bf(acc[j]);
    *(u16x8*)&out1[prow * 256 + m * 32 + gq * 8] = o;
}

// ---------------------------------------------------------------------------
extern "C" void kernel_launch(void* const* d_in, const int* in_sizes, int n_in,
                              void* d_out, int out_size, void* d_ws, size_t ws_size,
                              hipStream_t stream) {
    const float* f_recalib = (const float*)d_in[0];
    const float* f_orig    = (const float*)d_in[1];
    const float* offset_w  = (const float*)d_in[2];
    const float* offset_b  = (const float*)d_in[3];
    const float* attn_w    = (const float*)d_in[4];
    const float* attn_b    = (const float*)d_in[5];
    const float* value_w   = (const float*)d_in[6];
    const float* value_b   = (const float*)d_in[7];
    const float* proj_w    = (const float*)d_in[8];
    const float* proj_b    = (const float*)d_in[9];
    const float* mlp_w1    = (const float*)d_in[10];
    const float* mlp_b1    = (const float*)d_in[11];
    const float* mlp_w2    = (const float*)d_in[12];
    const float* mlp_b2    = (const float*)d_in[13];
    float* out = (float*)d_out;

    u16* wsb      = (u16*)d_ws;
    u16* x_pad    = wsb;                  // 8,921,088 u16 (17.8 MB), 66x66 padded
    u16* convout  = wsb + 8921088;        // 3,145,728 (6 MB)
    u16* value_bf = wsb + 12066816;       // 8,388,608 (16 MB)
    u16* out1_bf  = wsb + 20455424;       // 8,388,608 (16 MB)
    u16* wbf      = wsb + 28844032;       // 614,400 (1.2 MB) -> 58.9 MB total
    u16* out2_bf  = x_pad;                // alias: x_pad dead after conv+value
    u16* h_bf     = wsb + 8921088;        // alias convout+value+out1 (dead), 32 MB

    u16* wconv = wbf;
    u16* wval  = wbf + 221184;
    u16* wproj = wbf + 286720;
    u16* wmlp1 = wbf + 352256;
    u16* wmlp2 = wbf + 483328;

    prep_weights<<<2400, 256, 0, stream>>>(offset_w, attn_w, value_w, proj_w,
                                           mlp_w1, mlp_w2, wbf);
    zero_pad<<<8, 256, 0, stream>>>(x_pad);
    to_nhwc_pad<<<dim3(64, 4, 8), 256, 0, stream>>>(f_recalib, x_pad);
    conv3x3_mfma<<<dim3(64, 8), 256, 0, stream>>>(x_pad, wconv, offset_b, attn_b, convout);
    gemm128<<<dim3(32, 2, 8), 256, 0, stream>>>(x_pad, wval, value_b, nullptr,
                                                value_bf, nullptr, 256, 256, 0, 1);
    sample_attend_bf<<<dim3(64, 8, 8), 256, 0, stream>>>(value_bf, convout, out1_bf);
    // proj + f_orig -> d_out (f32 NCHW) AND out2_bf (bf16 NHWC), fused
    gemm128<<<dim3(32, 2, 8), 256, 0, stream>>>(out1_bf, wproj, proj_b, f_orig,
                                                out, out2_bf, 256, 256, 3, 0);
    gemm128<<<dim3(32, 4, 8), 256, 0, stream>>>(out2_bf, wmlp1, mlp_b1, nullptr,
                                                h_bf, nullptr, 256, 512, 1, 0);
    gemm128<<<dim3(32, 2, 8), 256, 0, stream>>>(h_bf, wmlp2, mlp_b2, out,
                                                out, nullptr, 512, 256, 2, 0);
}

// Round 8
// 150.106 us; speedup vs baseline: 5.8426x; 1.1131x over previous
//
#include <hip/hip_runtime.h>
#include <cstddef>

#define P_ 4096
#define PW_ 66   // padded width/height

using u16 = unsigned short;
typedef float  f32x4  __attribute__((ext_vector_type(4)));
typedef u16    u16x8  __attribute__((ext_vector_type(8)));
typedef u16    u16x4  __attribute__((ext_vector_type(4)));
typedef __bf16 bf16x8 __attribute__((ext_vector_type(8)));

#define DEVINL __device__ __forceinline__

DEVINL u16 f2bf(float f) {
    union { float f; unsigned u; } v; v.f = f;
    unsigned r = v.u + 0x7fffu + ((v.u >> 16) & 1u);
    return (u16)(r >> 16);
}
DEVINL float bf2f(u16 h) {
    union { unsigned u; float f; } v; v.u = ((unsigned)h) << 16;
    return v.f;
}

DEVINL f32x4 mfma16(u16x8 a, u16x8 b, f32x4 c) {
    return __builtin_amdgcn_mfma_f32_16x16x32_bf16(
        __builtin_bit_cast(bf16x8, a), __builtin_bit_cast(bf16x8, b), c, 0, 0, 0);
}

DEVINL void gload16(const u16* src, const u16* lds_dst) {
    __builtin_amdgcn_global_load_lds(
        (const __attribute__((address_space(1))) void*)src,
        (__attribute__((address_space(3))) void*)lds_dst, 16, 0, 0);
}

// ---------------------------------------------------------------------------
// prep_weights: all weights -> bf16. conv weights reordered to [tap][96][256].
// ---------------------------------------------------------------------------
__global__ void prep_weights(const float* __restrict__ off_w, const float* __restrict__ attn_w,
                             const float* __restrict__ val_w, const float* __restrict__ proj_w,
                             const float* __restrict__ w1, const float* __restrict__ w2,
                             u16* __restrict__ wbf) {
    int idx = blockIdx.x * 256 + threadIdx.x;
    if (idx >= 614400) return;
    float v;
    if (idx < 221184) {
        int tap = idx / 24576, rem = idx - tap * 24576, oc = rem >> 8, ic = rem & 255;
        v = (oc < 64) ? off_w[(size_t)(oc * 256 + ic) * 9 + tap]
                      : attn_w[(size_t)((oc - 64) * 256 + ic) * 9 + tap];
    } else if (idx < 286720) v = val_w[idx - 221184];
    else if (idx < 352256)   v = proj_w[idx - 286720];
    else if (idx < 483328)   v = w1[idx - 352256];
    else                     v = w2[idx - 483328];
    wbf[idx] = f2bf(v);
}

// ---------------------------------------------------------------------------
// zero the 260 pad pixels per batch of the padded NHWC image. grid (8).
// ---------------------------------------------------------------------------
__global__ __launch_bounds__(256) void zero_pad(u16* __restrict__ xp) {
    const int b = blockIdx.x, t = threadIdx.x;
    const u16x8 z = (u16x8){0, 0, 0, 0, 0, 0, 0, 0};
    for (int q = t; q < 8320; q += 256) {
        const int p = q >> 5, chunk = q & 31;
        int row, col;
        if (p < 66)       { row = 0;  col = p; }
        else if (p < 132) { row = 65; col = p - 66; }
        else { const int q2 = p - 132; row = 1 + (q2 >> 1); col = (q2 & 1) * 65; }
        *(u16x8*)&xp[((size_t)(b * PW_ + row) * PW_ + col) * 256 + chunk * 8] = z;
    }
}

// ---------------------------------------------------------------------------
// NCHW fp32 -> padded NHWC bf16. grid (64 y, 4 cgroup, 8 b), 256 thr.
// ---------------------------------------------------------------------------
__global__ __launch_bounds__(256) void to_nhwc_pad(const float* __restrict__ in,
                                                   u16* __restrict__ xp) {
    const int y = blockIdx.x, c0 = blockIdx.y * 64, b = blockIdx.z;
    __shared__ u16 ts[64 * 72];
    const int t = threadIdx.x, cl = t >> 4, xq = t & 15;
    #pragma unroll
    for (int r = 0; r < 4; ++r) {
        const int c = r * 16 + cl;
        const float4 v = *(const float4*)&in[((size_t)(b * 256 + c0 + c)) * P_ + y * 64 + xq * 4];
        ts[(xq * 4 + 0) * 72 + c] = f2bf(v.x);
        ts[(xq * 4 + 1) * 72 + c] = f2bf(v.y);
        ts[(xq * 4 + 2) * 72 + c] = f2bf(v.z);
        ts[(xq * 4 + 3) * 72 + c] = f2bf(v.w);
    }
    __syncthreads();
    const int px = t >> 2, seg = t & 3;
    u16x8 o0, o1;
    #pragma unroll
    for (int j = 0; j < 8; ++j) {
        o0[j] = ts[px * 72 + seg * 16 + j];
        o1[j] = ts[px * 72 + seg * 16 + 8 + j];
    }
    const size_t base = ((size_t)(b * PW_ + y + 1) * PW_ + 1 + px) * 256 + c0 + seg * 16;
    *(u16x8*)&xp[base]     = o0;
    *(u16x8*)&xp[base + 8] = o1;
}

// ---------------------------------------------------------------------------
// conv3x3 as 9 shifted full-GEMMs over padded input (unchanged from R7).
// ---------------------------------------------------------------------------
__global__ __launch_bounds__(256, 4) void conv3x3_mfma(
    const u16* __restrict__ xp, const u16* __restrict__ wconv,
    const float* __restrict__ off_b, const float* __restrict__ attn_b,
    u16* __restrict__ convout) {
    const int y = blockIdx.x, b = blockIdx.y;
    const int tid = threadIdx.x, w = tid >> 6, lane = tid & 63, g = lane >> 4, i = lane & 15;
    const int wm = w & 1, wn = w >> 1;
    const int srow = lane >> 4, sc = lane & 15;
    __shared__ u16 xs[64 * 128];     // [x 64][128 ic]
    __shared__ u16 wsL[96 * 128];    // [oc 96][128 ic]

    f32x4 acc[2][3];
    #pragma unroll
    for (int mi = 0; mi < 2; ++mi)
        #pragma unroll
        for (int nj = 0; nj < 3; ++nj) acc[mi][nj] = (f32x4){0.f, 0.f, 0.f, 0.f};

    for (int tap = 0; tap < 9; ++tap) {
        const int dy = tap / 3, dx = tap % 3;
        const u16* xrow = xp + ((size_t)(b * PW_ + y + dy) * PW_ + dx) * 256;
        const u16* wt = wconv + (size_t)(tap * 96) * 256;
        for (int cc = 0; cc < 2; ++cc) {
            const int kc = cc * 128;
            #pragma unroll
            for (int t = 0; t < 4; ++t) {
                const int j = w * 4 + t;
                const int row = j * 4 + srow;
                const int cs = sc ^ (row & 7);
                gload16(xrow + (size_t)row * 256 + kc + (cs << 3), &xs[j * 512]);
            }
            #pragma unroll
            for (int t = 0; t < 6; ++t) {
                const int j = w * 6 + t;
                const int row = j * 4 + srow;
                const int cs = sc ^ (row & 7);
                gload16(wt + (size_t)row * 256 + kc + (cs << 3), &wsL[j * 512]);
            }
            __syncthreads();
            #pragma unroll
            for (int ks = 0; ks < 4; ++ks) {
                u16x8 a[2], bb[3];
                #pragma unroll
                for (int mi = 0; mi < 2; ++mi) {
                    const int pr = wm * 32 + mi * 16 + i;
                    a[mi] = *(const u16x8*)&xs[pr * 128 + (((ks * 4 + g) ^ (pr & 7)) << 3)];
                }
                #pragma unroll
                for (int nj = 0; nj < 3; ++nj) {
                    const int ocr = wn * 48 + nj * 16 + i;
                    bb[nj] = *(const u16x8*)&wsL[ocr * 128 + (((ks * 4 + g) ^ (ocr & 7)) << 3)];
                }
                #pragma unroll
                for (int mi = 0; mi < 2; ++mi)
                    #pragma unroll
                    for (int nj = 0; nj < 3; ++nj)
                        acc[mi][nj] = mfma16(a[mi], bb[nj], acc[mi][nj]);
            }
            __syncthreads();
        }
    }
    #pragma unroll
    for (int mi = 0; mi < 2; ++mi) {
        const int x0 = wm * 32 + mi * 16 + g * 4;
        #pragma unroll
        for (int nj = 0; nj < 3; ++nj) {
            const int oc = wn * 48 + nj * 16 + i;
            const float bv = (oc < 64) ? off_b[oc] : attn_b[oc - 64];
            #pragma unroll
            for (int r = 0; r < 4; ++r)
                convout[((size_t)(b * P_ + y * 64 + x0 + r)) * 96 + oc] =
                    f2bf(acc[mi][nj][r] + bv);
        }
    }
}

// ---------------------------------------------------------------------------
// Double-buffered 128x128-tile NHWC bf16 GEMM, BK=64, counted vmcnt pipeline.
// grid (32, OC/128, 8), 256 thr (4 waves, 64x64 quadrants). LDS 64KB, 2 blk/CU.
// modes: 0 +bias -> bf16 NHWC(outB); 1 +bias+relu -> bf16 NHWC(outB);
//        4 +bias +resid f32 NCHW -> bf16 NHWC(outB) AND bf16 NCHW(outA);
//        5 +bias +resid bf16 NCHW -> f32 NCHW(outA).
// ---------------------------------------------------------------------------
__global__ __launch_bounds__(256, 2) void gemm_dbuf(
    const u16* __restrict__ X, const u16* __restrict__ W,
    const float* __restrict__ bias, const void* __restrict__ resid,
    void* __restrict__ outA, u16* __restrict__ outB,
    const int KTOT, const int OC, const int mode, const int padded) {
    const int px0 = blockIdx.x * 128, oc0 = blockIdx.y * 128, b = blockIdx.z;
    const int tid = threadIdx.x, w = tid >> 6, lane = tid & 63, g = lane >> 4, i = lane & 15;
    const int wm = w & 1, wn = w >> 1;
    __shared__ u16 lds[32768];           // 64 KB
    u16* xs = lds;                       // [2][8192]  (128 rows x 64 u16 per buf)
    u16* wsL = lds + 16384;              // [2][8192]

    const int srcC = (lane & 7) ^ ((lane >> 3) & 7);   // inverse-swizzled src chunk

    f32x4 acc[4][4];
    #pragma unroll
    for (int mi = 0; mi < 4; ++mi)
        #pragma unroll
        for (int nj = 0; nj < 4; ++nj) acc[mi][nj] = (f32x4){0.f, 0.f, 0.f, 0.f};

    const int NC = KTOT >> 6;

    auto stage = [&](int buf, int kc) {
        #pragma unroll
        for (int t = 0; t < 4; ++t) {
            const int j = w * 4 + t;
            const int row = j * 8 + (lane >> 3);
            const u16* sx;
            if (padded) {
                const int pxg = px0 + row;
                sx = X + ((size_t)(b * PW_ + (pxg >> 6) + 1) * PW_ + (pxg & 63) + 1) * 256
                       + kc + (srcC << 3);
            } else {
                sx = X + (size_t)(b * P_ + px0 + row) * KTOT + kc + (srcC << 3);
            }
            gload16(sx, &xs[buf * 8192 + j * 512]);
        }
        #pragma unroll
        for (int t = 0; t < 4; ++t) {
            const int j = w * 4 + t;
            const int row = j * 8 + (lane >> 3);
            gload16(W + (size_t)(oc0 + row) * KTOT + kc + (srcC << 3),
                    &wsL[buf * 8192 + j * 512]);
        }
    };

    stage(0, 0);
    stage(1, 64);
    asm volatile("s_waitcnt vmcnt(8)" ::: "memory");   // chunk0 landed; chunk1 in flight
    __builtin_amdgcn_s_barrier();

    for (int c = 0; c < NC; ++c) {
        const u16* xb = &xs[(c & 1) * 8192];
        const u16* wb = &wsL[(c & 1) * 8192];
        #pragma unroll
        for (int ks = 0; ks < 2; ++ks) {
            u16x8 a[4], bb[4];
            #pragma unroll
            for (int mi = 0; mi < 4; ++mi) {
                const int row = wm * 64 + mi * 16 + i;
                a[mi] = *(const u16x8*)&xb[row * 64 + (((ks * 4 + g) ^ (row & 7)) << 3)];
            }
            #pragma unroll
            for (int nj = 0; nj < 4; ++nj) {
                const int row = wn * 64 + nj * 16 + i;
                bb[nj] = *(const u16x8*)&wb[row * 64 + (((ks * 4 + g) ^ (row & 7)) << 3)];
            }
            #pragma unroll
            for (int mi = 0; mi < 4; ++mi)
                #pragma unroll
                for (int nj = 0; nj < 4; ++nj)
                    acc[mi][nj] = mfma16(a[mi], bb[nj], acc[mi][nj]);
        }
        __builtin_amdgcn_sched_barrier(0);
        __builtin_amdgcn_s_barrier();            // all waves done reading buf c&1
        if (c + 2 < NC) {
            stage(c & 1, (c + 2) << 6);          // overwrite just-consumed buffer
            asm volatile("s_waitcnt vmcnt(8)" ::: "memory");  // chunk c+1 landed
        } else {
            asm volatile("s_waitcnt vmcnt(0)" ::: "memory");
        }
        __builtin_amdgcn_s_barrier();            // next buffer visible to all
    }

    // ---------------- epilogue: LDS f32 transpose, vectorized stores ---------
    float* lf = (float*)lds;                     // [128 oc][66 px] per half
    const int pxq = tid >> 2, segq = tid & 3;    // NHWC store mapping
    const int oclh = tid >> 1, shh = (tid & 1) * 32;  // oc-row mapping

    #pragma unroll
    for (int h = 0; h < 2; ++h) {
        if (wm == h) {
            #pragma unroll
            for (int nj = 0; nj < 4; ++nj) {
                const int ocl = wn * 64 + nj * 16 + i;
                const float bv = bias[oc0 + ocl];
                #pragma unroll
                for (int mi = 0; mi < 4; ++mi)
                    #pragma unroll
                    for (int r = 0; r < 4; ++r)
                        lf[ocl * 66 + mi * 16 + g * 4 + r] = acc[mi][nj][r] + bv;
            }
        }
        __syncthreads();
        const int pxg0 = px0 + h * 64;

        if (mode == 4) {                         // += f_orig (f32 NCHW), coalesced
            const float* rf = (const float*)resid;
            const size_t rb = ((size_t)b * 256 + oc0 + oclh) * P_ + pxg0 + shh;
            #pragma unroll
            for (int q = 0; q < 8; ++q) {
                const float4 r4 = *(const float4*)&rf[rb + q * 4];
                lf[oclh * 66 + shh + q * 4 + 0] += r4.x;
                lf[oclh * 66 + shh + q * 4 + 1] += r4.y;
                lf[oclh * 66 + shh + q * 4 + 2] += r4.z;
                lf[oclh * 66 + shh + q * 4 + 3] += r4.w;
            }
            __syncthreads();
        }

        if (mode <= 1 || mode == 4) {            // bf16 NHWC store, 16B/lane
            const size_t nb = ((size_t)(b * P_ + pxg0 + pxq)) * OC + oc0 + segq * 32;
            #pragma unroll
            for (int t2 = 0; t2 < 4; ++t2) {
                u16x8 o8;
                #pragma unroll
                for (int jj = 0; jj < 8; ++jj) {
                    float v = lf[(segq * 32 + t2 * 8 + jj) * 66 + pxq];
                    if (mode == 1) v = fmaxf(v, 0.f);
                    o8[jj] = f2bf(v);
                }
                *(u16x8*)&outB[nb + t2 * 8] = o8;
            }
        }
        if (mode == 4) {                         // bf16 NCHW copy (mlp2 residual)
            u16* on = (u16*)outA;
            const size_t cb = ((size_t)b * 256 + oc0 + oclh) * P_ + pxg0 + shh;
            #pragma unroll
            for (int t2 = 0; t2 < 4; ++t2) {
                u16x8 o8;
                #pragma unroll
                for (int jj = 0; jj < 8; ++jj)
                    o8[jj] = f2bf(lf[oclh * 66 + shh + t2 * 8 + jj]);
                *(u16x8*)&on[cb + t2 * 8] = o8;
            }
        }
        if (mode == 5) {                         // += bf16 NCHW resid, f32 NCHW out
            const u16* rb16 = (const u16*)resid;
            float* of = (float*)outA;
            const size_t cb = ((size_t)b * 256 + oc0 + oclh) * P_ + pxg0 + shh;
            #pragma unroll
            for (int q = 0; q < 8; ++q) {
                const u16x4 r4 = *(const u16x4*)&rb16[cb + q * 4];
                float4 o;
                o.x = lf[oclh * 66 + shh + q * 4 + 0] + bf2f(r4[0]);
                o.y = lf[oclh * 66 + shh + q * 4 + 1] + bf2f(r4[1]);
                o.z = lf[oclh * 66 + shh + q * 4 + 2] + bf2f(r4[2]);
                o.w = lf[oclh * 66 + shh + q * 4 + 3] + bf2f(r4[3]);
                *(float4*)&of[cb + q * 4] = o;
            }
        }
        __syncthreads();
    }
}

// ---------------------------------------------------------------------------
// softmax over K + bilinear grid-sample + weighted sum. NHWC bf16 in/out.
// ---------------------------------------------------------------------------
__global__ __launch_bounds__(256) void sample_attend_bf(
    const u16* __restrict__ value, const u16* __restrict__ conv,
    u16* __restrict__ out1) {
    const int y = blockIdx.x, m = blockIdx.y, b = blockIdx.z;
    const int tid = threadIdx.x, x = tid >> 2, gq = tid & 3;
    const size_t prow = (size_t)(b * P_ + y * 64 + x);

    const u16x8 ov = *(const u16x8*)&conv[prow * 96 + m * 8];
    const u16x4 av = *(const u16x4*)&conv[prow * 96 + 64 + m * 4];

    float a[4];
    #pragma unroll
    for (int k = 0; k < 4; ++k) a[k] = bf2f(av[k]);
    const float mx = fmaxf(fmaxf(a[0], a[1]), fmaxf(a[2], a[3]));
    float s = 0.f;
    #pragma unroll
    for (int k = 0; k < 4; ++k) { a[k] = __expf(a[k] - mx); s += a[k]; }
    const float inv = 1.f / s;

    float acc[8];
    #pragma unroll
    for (int j = 0; j < 8; ++j) acc[j] = 0.f;

    const u16* vb = value + ((size_t)b * P_) * 256 + m * 32 + gq * 8;

    #pragma unroll
    for (int k = 0; k < 4; ++k) {
        const float offx = bf2f(ov[2 * k]), offy = bf2f(ov[2 * k + 1]);
        const float px = (float)(63 - x) + offx;
        const float py = (float)y + offy;
        const float x0f = floorf(px), y0f = floorf(py);
        const int xi0 = (int)x0f, yi0 = (int)y0f;
        const float wx = px - x0f, wy = py - y0f;
        const int xi1 = xi0 + 1, yi1 = yi0 + 1;
        const bool vx0 = (xi0 >= 0) & (xi0 <= 63), vx1 = (xi1 >= 0) & (xi1 <= 63);
        const bool vy0 = (yi0 >= 0) & (yi0 <= 63), vy1 = (yi1 >= 0) & (yi1 <= 63);
        const int cx0 = min(max(xi0, 0), 63), cx1 = min(max(xi1, 0), 63);
        const int cy0 = min(max(yi0, 0), 63), cy1 = min(max(yi1, 0), 63);
        const float ak = a[k] * inv;
        const float c00 = ak * (1.f - wx) * (1.f - wy) * ((vx0 & vy0) ? 1.f : 0.f);
        const float c01 = ak * wx * (1.f - wy) * ((vx1 & vy0) ? 1.f : 0.f);
        const float c10 = ak * (1.f - wx) * wy * ((vx0 & vy1) ? 1.f : 0.f);
        const float c11 = ak * wx * wy * ((vx1 & vy1) ? 1.f : 0.f);
        const u16x8 v00 = *(const u16x8*)&vb[(size_t)(cy0 * 64 + cx0) * 256];
        const u16x8 v01 = *(const u16x8*)&vb[(size_t)(cy0 * 64 + cx1) * 256];
        const u16x8 v10 = *(const u16x8*)&vb[(size_t)(cy1 * 64 + cx0) * 256];
        const u16x8 v11 = *(const u16x8*)&vb[(size_t)(cy1 * 64 + cx1) * 256];
        #pragma unroll
        for (int j = 0; j < 8; ++j)
            acc[j] += c00 * bf2f(v00[j]) + c01 * bf2f(v01[j])
                    + c10 * bf2f(v10[j]) + c11 * bf2f(v11[j]);
    }
    u16x8 o;
    #pragma unroll
    for (int j = 0; j < 8; ++j) o[j] = f2bf(acc[j]);
    *(u16x8*)&out1[prow * 256 + m * 32 + gq * 8] = o;
}

// ---------------------------------------------------------------------------
extern "C" void kernel_launch(void* const* d_in, const int* in_sizes, int n_in,
                              void* d_out, int out_size, void* d_ws, size_t ws_size,
                              hipStream_t stream) {
    const float* f_recalib = (const float*)d_in[0];
    const float* f_orig    = (const float*)d_in[1];
    const float* offset_w  = (const float*)d_in[2];
    const float* offset_b  = (const float*)d_in[3];
    const float* attn_w    = (const float*)d_in[4];
    const float* attn_b    = (const float*)d_in[5];
    const float* value_w   = (const float*)d_in[6];
    const float* value_b   = (const float*)d_in[7];
    const float* proj_w    = (const float*)d_in[8];
    const float* proj_b    = (const float*)d_in[9];
    const float* mlp_w1    = (const float*)d_in[10];
    const float* mlp_b1    = (const float*)d_in[11];
    const float* mlp_w2    = (const float*)d_in[12];
    const float* mlp_b2    = (const float*)d_in[13];
    float* out = (float*)d_out;

    u16* wsb       = (u16*)d_ws;
    u16* x_pad     = wsb;                  // 8,921,088 u16 (17.8 MB)
    u16* convout   = wsb + 8921088;        // 3,145,728 (6 MB)
    u16* value_bf  = wsb + 12066816;       // 8,388,608 (16 MB)
    u16* out1_bf   = wsb + 20455424;       // 8,388,608 (16 MB)
    u16* wbf       = wsb + 28844032;       // 614,400 (1.2 MB)
    u16* out2_nchw = wsb + 29458432;       // 8,388,608 (16 MB) -> 75.7 MB total
    u16* out2_bf   = x_pad;                // alias: x_pad dead after conv+value
    u16* h_bf      = wsb + 8921088;        // alias convout+value+out1 (dead), 32 MB

    u16* wconv = wbf;
    u16* wval  = wbf + 221184;
    u16* wproj = wbf + 286720;
    u16* wmlp1 = wbf + 352256;
    u16* wmlp2 = wbf + 483328;

    prep_weights<<<2400, 256, 0, stream>>>(offset_w, attn_w, value_w, proj_w,
                                           mlp_w1, mlp_w2, wbf);
    zero_pad<<<8, 256, 0, stream>>>(x_pad);
    to_nhwc_pad<<<dim3(64, 4, 8), 256, 0, stream>>>(f_recalib, x_pad);
    conv3x3_mfma<<<dim3(64, 8), 256, 0, stream>>>(x_pad, wconv, offset_b, attn_b, convout);
    gemm_dbuf<<<dim3(32, 2, 8), 256, 0, stream>>>(x_pad, wval, value_b, nullptr,
                                                  nullptr, value_bf, 256, 256, 0, 1);
    sample_attend_bf<<<dim3(64, 8, 8), 256, 0, stream>>>(value_bf, convout, out1_bf);
    // proj + f_orig -> out2_bf (bf16 NHWC, mlp1 input) + out2_nchw (bf16 NCHW, mlp2 resid)
    gemm_dbuf<<<dim3(32, 2, 8), 256, 0, stream>>>(out1_bf, wproj, proj_b, f_orig,
                                                  out2_nchw, out2_bf, 256, 256, 4, 0);
    gemm_dbuf<<<dim3(32, 4, 8), 256, 0, stream>>>(out2_bf, wmlp1, mlp_b1, nullptr,
                                                  nullptr, h_bf, 256, 512, 1, 0);
    // final: mlp2(h) + out2 -> d_out (f32 NCHW)
    gemm_dbuf<<<dim3(32, 2, 8), 256, 0, stream>>>(h_bf, wmlp2, mlp_b2, out2_nchw,
                                                  out, nullptr, 512, 256, 5, 0);
}